// Round 3
// baseline (786.316 us; speedup 1.0000x reference)
//
#include <hip/hip_runtime.h>
#include <hip/hip_bf16.h>
#include <cstdint>
#include <math.h>

typedef unsigned short u16;
typedef __bf16 bh;
typedef bh bh8 __attribute__((ext_vector_type(8)));
typedef float f32x4 __attribute__((ext_vector_type(4)));

#define SCALE_F 0.04419417382415922f  // 512^-0.5

__device__ __forceinline__ float bf2f(u16 u) {
    union { float f; unsigned int i; } v; v.i = ((unsigned int)u) << 16; return v.f;
}
__device__ __forceinline__ u16 f2bf(float f) {
    __hip_bfloat16 h = __float2bfloat16(f);
    return __builtin_bit_cast(u16, h);
}

// load 8 contiguous fp32, round to bf16x8
__device__ __forceinline__ bh8 ld8_f32(const float* p) {
    float4 f0 = *(const float4*)p;
    float4 f1 = *(const float4*)(p + 4);
    bh8 r;
    r[0] = (bh)f0.x; r[1] = (bh)f0.y; r[2] = (bh)f0.z; r[3] = (bh)f0.w;
    r[4] = (bh)f1.x; r[5] = (bh)f1.y; r[6] = (bh)f1.z; r[7] = (bh)f1.w;
    return r;
}

// ---------------------------------------------------------------------------
// transpose + downcast: in fp32 [R, C] -> out bf16 [C, R]
__global__ void transpose_bf(const float* __restrict__ in, u16* __restrict__ out,
                             int R, int C) {
    __shared__ float t[32][33];
    int bx = blockIdx.x * 32, by = blockIdx.y * 32;
    int x = threadIdx.x, y = threadIdx.y;
    for (int i = 0; i < 32; i += 8)
        t[y + i][x] = in[(size_t)(by + y + i) * C + bx + x];
    __syncthreads();
    for (int i = 0; i < 32; i += 8)
        out[(size_t)(bx + y + i) * R + by + x] = f2bf(t[x][y + i]);
}

// ---------------------------------------------------------------------------
// NT GEMM: out[M,N] = act(A[M,K] @ B[N,K]^T + bias) (+ prior bf16 C if ADD).
// A bf16 (AF32=0) or fp32 (AF32=1) row-major; B bf16 row-major (pre-transposed).
// bias fp32. F32OUT: write fp32 to C, else bf16 to Cbf.
// ACT: 0 none, 1 relu, 2 leaky_relu(0.01). M%128==0, N%128==0, K%32==0.
template<int ACT, int ADD, int F32OUT, int AF32>
__global__ __launch_bounds__(256) void gemm_nt(
    const void* __restrict__ Av, const u16* __restrict__ B,
    const float* __restrict__ bias, float* __restrict__ C,
    u16* __restrict__ Cbf, int M, int N, int K)
{
    __shared__ __align__(16) u16 Alds[128 * 40];
    __shared__ __align__(16) u16 Blds[128 * 40];
    const int tid = threadIdx.x;
    const int m0 = blockIdx.y * 128, n0 = blockIdx.x * 128;
    const int lane = tid & 63, wave = tid >> 6;
    const int wm = (wave & 1) * 64, wn = (wave >> 1) * 64;
    const int lr = lane & 15, quad = lane >> 4;
    const int r0 = tid >> 2, k8 = (tid & 3) * 8;
    const int r1 = r0 + 64;

    const u16*   Ab = (const u16*)Av;
    const float* Af = (const float*)Av;
    const u16* Arow0b = Ab + (size_t)(m0 + r0) * K + k8;
    const u16* Arow1b = Ab + (size_t)(m0 + r1) * K + k8;
    const float* Arow0f = Af + (size_t)(m0 + r0) * K + k8;
    const float* Arow1f = Af + (size_t)(m0 + r1) * K + k8;
    const u16* Brow0 = B + (size_t)(n0 + r0) * K + k8;
    const u16* Brow1 = B + (size_t)(n0 + r1) * K + k8;

    f32x4 acc[4][4] = {};
    bh8 pa0, pa1, pb0, pb1;
    if (AF32) { pa0 = ld8_f32(Arow0f); pa1 = ld8_f32(Arow1f); }
    else      { pa0 = *(const bh8*)Arow0b; pa1 = *(const bh8*)Arow1b; }
    pb0 = *(const bh8*)Brow0;
    pb1 = *(const bh8*)Brow1;

    for (int k0 = 0; k0 < K; k0 += 32) {
        __syncthreads();
        *(bh8*)&Alds[r0 * 40 + k8] = pa0;
        *(bh8*)&Alds[r1 * 40 + k8] = pa1;
        *(bh8*)&Blds[r0 * 40 + k8] = pb0;
        *(bh8*)&Blds[r1 * 40 + k8] = pb1;
        __syncthreads();
        if (k0 + 32 < K) {
            if (AF32) { pa0 = ld8_f32(Arow0f + k0 + 32); pa1 = ld8_f32(Arow1f + k0 + 32); }
            else      { pa0 = *(const bh8*)(Arow0b + k0 + 32); pa1 = *(const bh8*)(Arow1b + k0 + 32); }
            pb0 = *(const bh8*)(Brow0 + k0 + 32);
            pb1 = *(const bh8*)(Brow1 + k0 + 32);
        }
        bh8 af[4], bfr[4];
        #pragma unroll
        for (int i = 0; i < 4; i++) {
            af[i]  = *(const bh8*)&Alds[(wm + i * 16 + lr) * 40 + quad * 8];
            bfr[i] = *(const bh8*)&Blds[(wn + i * 16 + lr) * 40 + quad * 8];
        }
        #pragma unroll
        for (int mi = 0; mi < 4; mi++)
            #pragma unroll
            for (int ni = 0; ni < 4; ni++)
                acc[mi][ni] = __builtin_amdgcn_mfma_f32_16x16x32_bf16(
                    af[mi], bfr[ni], acc[mi][ni], 0, 0, 0);
    }

    #pragma unroll
    for (int ni = 0; ni < 4; ni++) {
        int col = n0 + wn + ni * 16 + lr;
        float bs = bias[col];
        #pragma unroll
        for (int mi = 0; mi < 4; mi++) {
            #pragma unroll
            for (int i = 0; i < 4; i++) {
                int row = m0 + wm + mi * 16 + quad * 4 + i;
                float v = acc[mi][ni][i] + bs;
                if (ACT == 1) v = fmaxf(v, 0.0f);
                if (ACT == 2) v = (v > 0.0f) ? v : 0.01f * v;
                size_t o = (size_t)row * N + col;
                if (ADD) v += bf2f(Cbf[o]);
                if (F32OUT) C[o] = v;
                else        Cbf[o] = f2bf(v);
            }
        }
    }
}

// ---------------------------------------------------------------------------
// Fused logits GEMM + per-row running top-6 over a 1024-column chunk.
// A = e_h bf16 [8192,512], B = e_t bf16 [8192,512] (NT). Writes partial
// top-6 (value scaled by SCALE, col index) per (row, chunk).
__global__ __launch_bounds__(256) void logits_topk(
    const u16* __restrict__ Ah, const u16* __restrict__ Bt,
    float* __restrict__ tvp, int* __restrict__ tip)
{
    const int K = 512;
    __shared__ __align__(16) u16 Alds[128 * 40];
    __shared__ __align__(16) u16 Blds[128 * 40];
    __shared__ float S[128 * 65];
    __shared__ float tv[128 * 6];
    __shared__ int   ti[128 * 6];
    const int tid = threadIdx.x;
    const int m0 = blockIdx.y * 128;
    const int chunk = blockIdx.x;          // 0..7, 1024 cols each
    const int lane = tid & 63, wave = tid >> 6;
    const int wm = (wave & 1) * 64, wn = (wave >> 1) * 64;
    const int lr = lane & 15, quad = lane >> 4;
    const int r0 = tid >> 2, k8 = (tid & 3) * 8;
    const int r1 = r0 + 64;

    for (int i = tid; i < 128 * 6; i += 256) { tv[i] = -INFINITY; ti[i] = 0; }

    const u16* Arow0 = Ah + (size_t)(m0 + r0) * K + k8;
    const u16* Arow1 = Ah + (size_t)(m0 + r1) * K + k8;

    for (int nt = 0; nt < 8; nt++) {
        int n0 = chunk * 1024 + nt * 128;
        const u16* Brow0 = Bt + (size_t)(n0 + r0) * K + k8;
        const u16* Brow1 = Bt + (size_t)(n0 + r1) * K + k8;
        f32x4 acc[4][4] = {};
        bh8 pa0 = *(const bh8*)(Arow0);
        bh8 pa1 = *(const bh8*)(Arow1);
        bh8 pb0 = *(const bh8*)(Brow0);
        bh8 pb1 = *(const bh8*)(Brow1);
        for (int k0 = 0; k0 < K; k0 += 32) {
            __syncthreads();
            *(bh8*)&Alds[r0 * 40 + k8] = pa0;
            *(bh8*)&Alds[r1 * 40 + k8] = pa1;
            *(bh8*)&Blds[r0 * 40 + k8] = pb0;
            *(bh8*)&Blds[r1 * 40 + k8] = pb1;
            __syncthreads();
            if (k0 + 32 < K) {
                pa0 = *(const bh8*)(Arow0 + k0 + 32);
                pa1 = *(const bh8*)(Arow1 + k0 + 32);
                pb0 = *(const bh8*)(Brow0 + k0 + 32);
                pb1 = *(const bh8*)(Brow1 + k0 + 32);
            }
            bh8 af[4], bfr[4];
            #pragma unroll
            for (int i = 0; i < 4; i++) {
                af[i]  = *(const bh8*)&Alds[(wm + i * 16 + lr) * 40 + quad * 8];
                bfr[i] = *(const bh8*)&Blds[(wn + i * 16 + lr) * 40 + quad * 8];
            }
            #pragma unroll
            for (int mi = 0; mi < 4; mi++)
                #pragma unroll
                for (int ni = 0; ni < 4; ni++)
                    acc[mi][ni] = __builtin_amdgcn_mfma_f32_16x16x32_bf16(
                        af[mi], bfr[ni], acc[mi][ni], 0, 0, 0);
        }
        // stage 64-col halves to LDS, scan rows sequentially (stable order)
        for (int half = 0; half < 2; half++) {
            __syncthreads();
            if ((wave >> 1) == half) {
                #pragma unroll
                for (int mi = 0; mi < 4; mi++)
                    #pragma unroll
                    for (int ni = 0; ni < 4; ni++)
                        #pragma unroll
                        for (int i = 0; i < 4; i++)
                            S[(wm + mi * 16 + quad * 4 + i) * 65 + ni * 16 + lr]
                                = acc[mi][ni][i];
            }
            __syncthreads();
            if (tid < 128) {
                float* tvr = &tv[tid * 6];
                int*   tir = &ti[tid * 6];
                int cb = n0 + half * 64;
                for (int c = 0; c < 64; c++) {
                    float val = S[tid * 65 + c] * SCALE_F;
                    if (val > tvr[5]) {
                        int id = cb + c;
                        #pragma unroll
                        for (int j = 0; j < 6; j++) {
                            if (val > tvr[j]) {
                                for (int t2 = 5; t2 > j; t2--) {
                                    tvr[t2] = tvr[t2 - 1]; tir[t2] = tir[t2 - 1];
                                }
                                tvr[j] = val; tir[j] = id; break;
                            }
                        }
                    }
                }
            }
        }
    }
    __syncthreads();
    for (int i = tid; i < 128 * 6; i += 256) {
        int r = i / 6, j = i - r * 6;
        tvp[(size_t)(m0 + r) * 48 + chunk * 6 + j] = tv[i];
        tip[(size_t)(m0 + r) * 48 + chunk * 6 + j] = ti[i];
    }
}

// Merge 8 partial top-6 lists per row -> final top-6.
__global__ void topk_merge(const float* __restrict__ tvp, const int* __restrict__ tip,
                           float* __restrict__ tv, int* __restrict__ ti)
{
    int r = blockIdx.x * 256 + threadIdx.x;
    float v[6]; int ix[6];
    #pragma unroll
    for (int j = 0; j < 6; j++) { v[j] = -INFINITY; ix[j] = 0; }
    const float* pv = tvp + (size_t)r * 48;
    const int*   pi = tip + (size_t)r * 48;
    for (int c = 0; c < 48; c++) {
        float val = pv[c]; int id = pi[c];
        if (val > v[5]) {
            #pragma unroll
            for (int j = 0; j < 6; j++) {
                if (val > v[j]) {
                    #pragma unroll
                    for (int t = 5; t > j; t--) { v[t] = v[t - 1]; ix[t] = ix[t - 1]; }
                    v[j] = val; ix[j] = id; break;
                }
            }
        }
    }
    #pragma unroll
    for (int j = 0; j < 6; j++) { tv[(size_t)r * 6 + j] = v[j]; ti[(size_t)r * 6 + j] = ix[j]; }
}

// ---------------------------------------------------------------------------
// Per-row neighbor aggregation (bf16 inputs, fp32 math): p=softmax(tw);
// gate/ka/kp/e_Nh; emits s1 = bf16(e_h + e_Nh), s2 = bf16(e_h * e_Nh).
__global__ __launch_bounds__(256) void neighbor_kernel(
    const u16* __restrict__ eH, const u16* __restrict__ eT,
    const float* __restrict__ tv, const int* __restrict__ ti,
    u16* __restrict__ s1, u16* __restrict__ s2)
{
    __shared__ float red[256];
    __shared__ float ka_sh[6];
    const int n = blockIdx.x, tid = threadIdx.x;
    float tw[6]; int id[6];
    #pragma unroll
    for (int j = 0; j < 6; j++) {
        tw[j] = tv[n * 6 + j];
        int t = ti[n * 6 + j];
        id[j] = ((unsigned)t < 8192u) ? t : 0;   // guard vs wild gather
    }
    float mx = tw[0];
    #pragma unroll
    for (int j = 1; j < 6; j++) mx = fmaxf(mx, tw[j]);
    float p[6]; float ps = 0.f;
    #pragma unroll
    for (int j = 0; j < 6; j++) { p[j] = __expf(tw[j] - mx); ps += p[j]; }
    float inv = 1.0f / ps;
    #pragma unroll
    for (int j = 0; j < 6; j++) p[j] *= inv;

    const size_t base = (size_t)n * 512;
    float eh0 = bf2f(eH[base + tid]), eh1 = bf2f(eH[base + tid + 256]);
    float nb0[6], nb1[6];
    #pragma unroll
    for (int j = 0; j < 6; j++) {
        size_t b = (size_t)id[j] * 512;
        nb0[j] = bf2f(eT[b + tid]); nb1[j] = bf2f(eT[b + tid + 256]);
    }
    float kap[6];
    #pragma unroll
    for (int j = 0; j < 6; j++) {
        float e0 = p[j] * nb0[j] + (1.f - p[j]) * eh0;
        float e1 = p[j] * nb1[j] + (1.f - p[j]) * eh1;
        float g0 = tanhf(eh0 + e0), g1 = tanhf(eh1 + e1);
        kap[j] = nb0[j] * g0 + nb1[j] * g1;
    }
    for (int j = 0; j < 6; j++) {
        red[tid] = kap[j];
        __syncthreads();
        for (int s = 128; s > 0; s >>= 1) {
            if (tid < s) red[tid] += red[tid + s];
            __syncthreads();
        }
        if (tid == 0) ka_sh[j] = red[0];
        __syncthreads();
    }
    float ka[6];
    #pragma unroll
    for (int j = 0; j < 6; j++) ka[j] = ka_sh[j];
    float m2 = ka[0];
    #pragma unroll
    for (int j = 1; j < 6; j++) m2 = fmaxf(m2, ka[j]);
    float kp[6]; float ks = 0.f;
    #pragma unroll
    for (int j = 0; j < 6; j++) { kp[j] = __expf(ka[j] - m2); ks += kp[j]; }
    float inv2 = 1.0f / ks;
    #pragma unroll
    for (int j = 0; j < 6; j++) kp[j] *= inv2;
    float eN0 = 0.f, eN1 = 0.f;
    #pragma unroll
    for (int j = 0; j < 6; j++) { eN0 += kp[j] * nb0[j]; eN1 += kp[j] * nb1[j]; }
    s1[base + tid]       = f2bf(eh0 + eN0);
    s1[base + tid + 256] = f2bf(eh1 + eN1);
    s2[base + tid]       = f2bf(eh0 * eN0);
    s2[base + tid + 256] = f2bf(eh1 * eN1);
}

// ---------------------------------------------------------------------------
__global__ void colsum_kernel(const u16* __restrict__ h, float* __restrict__ colsum) {
    int tid = threadIdx.x;
    int n0 = blockIdx.x * 256;
    float a0 = 0.f, a1 = 0.f;
    for (int k = 0; k < 256; k++) {
        size_t b = (size_t)(n0 + k) * 512;
        a0 += bf2f(h[b + tid]); a1 += bf2f(h[b + tid + 256]);
    }
    atomicAdd(&colsum[tid], a0);
    atomicAdd(&colsum[tid + 256], a1);
}

__global__ void meanmix_kernel(u16* __restrict__ h, const float* __restrict__ colsum) {
    size_t i = (size_t)blockIdx.x * 256 + threadIdx.x;
    int col = (int)(i & 511);
    h[i] = f2bf((bf2f(h[i]) + colsum[col] * (1.0f / 8192.0f)) * 0.5f);
}

// att2: att[n] = dot(a1[n,:256], w) + b. One wave per row.
__global__ __launch_bounds__(256) void att2_kernel(
    const float* __restrict__ a1, const float* __restrict__ w,
    const float* __restrict__ b, float* __restrict__ att)
{
    int row = blockIdx.x * 4 + (threadIdx.x >> 6);
    int lane = threadIdx.x & 63;
    const float* pr = a1 + (size_t)row * 256;
    float s = 0.f;
    #pragma unroll
    for (int k = 0; k < 4; k++) { int c = lane + k * 64; s += pr[c] * w[c]; }
    #pragma unroll
    for (int off = 32; off > 0; off >>= 1) s += __shfl_down(s, off);
    if (lane == 0) att[row] = s + b[0];
}

__global__ void att_prep(const float* __restrict__ att, float* __restrict__ scal) {
    __shared__ float red[256];
    int tid = threadIdx.x;
    float mx = -INFINITY;
    for (int i = tid; i < 8192; i += 256) mx = fmaxf(mx, att[i]);
    red[tid] = mx; __syncthreads();
    for (int s = 128; s > 0; s >>= 1) {
        if (tid < s) red[tid] = fmaxf(red[tid], red[tid + s]);
        __syncthreads();
    }
    mx = red[0]; __syncthreads();
    float sm = 0.f;
    for (int i = tid; i < 8192; i += 256) sm += __expf(att[i] - mx);
    red[tid] = sm; __syncthreads();
    for (int s = 128; s > 0; s >>= 1) {
        if (tid < s) red[tid] += red[tid + s];
        __syncthreads();
    }
    if (tid == 0) { scal[0] = mx; scal[1] = red[0]; }
}

__global__ void pooled_kernel(const u16* __restrict__ emb, const float* __restrict__ att,
                              const float* __restrict__ scal, float* __restrict__ pooled) {
    int tid = threadIdx.x;
    int n0 = blockIdx.x * 256;
    float mx = scal[0]; float inv = 1.0f / scal[1];
    float a0 = 0.f, a1 = 0.f;
    for (int k = 0; k < 256; k++) {
        int n = n0 + k;
        float w = __expf(att[n] - mx) * inv;
        size_t b = (size_t)n * 512;
        a0 += w * bf2f(emb[b + tid]);
        a1 += w * bf2f(emb[b + tid + 256]);
    }
    atomicAdd(&pooled[tid], a0);
    atomicAdd(&pooled[tid + 256], a1);
}

__global__ void final_kernel(const float* __restrict__ pooled,
                             const float* __restrict__ g, const float* __restrict__ bln,
                             const float* __restrict__ fcw, const float* __restrict__ fcb,
                             float* __restrict__ out) {
    __shared__ float red[256];
    int tid = threadIdx.x;
    float x0 = pooled[tid], x1 = pooled[tid + 256];
    red[tid] = x0 + x1; __syncthreads();
    for (int s = 128; s > 0; s >>= 1) { if (tid < s) red[tid] += red[tid + s]; __syncthreads(); }
    float mu = red[0] * (1.0f / 512.0f); __syncthreads();
    float d0 = x0 - mu, d1 = x1 - mu;
    red[tid] = d0 * d0 + d1 * d1; __syncthreads();
    for (int s = 128; s > 0; s >>= 1) { if (tid < s) red[tid] += red[tid + s]; __syncthreads(); }
    float var = red[0] * (1.0f / 512.0f); __syncthreads();
    float rstd = rsqrtf(var + 1e-5f);
    float l0 = d0 * rstd * g[tid]       + bln[tid];
    float l1 = d1 * rstd * g[tid + 256] + bln[tid + 256];
    red[tid] = l0 * fcw[tid * 2] + l1 * fcw[(tid + 256) * 2]; __syncthreads();
    for (int s = 128; s > 0; s >>= 1) { if (tid < s) red[tid] += red[tid + s]; __syncthreads(); }
    float o0 = red[0] + fcb[0]; __syncthreads();
    red[tid] = l0 * fcw[tid * 2 + 1] + l1 * fcw[(tid + 256) * 2 + 1]; __syncthreads();
    for (int s = 128; s > 0; s >>= 1) { if (tid < s) red[tid] += red[tid + s]; __syncthreads(); }
    float o1 = red[0] + fcb[1];
    if (tid == 0) {
        float m = fmaxf(o0, o1);
        float e0 = expf(o0 - m), e1 = expf(o1 - m);
        float se = e0 + e1;
        out[0] = o0;
        out[1] = o1;
        out[2] = e0 / se;
        out[3] = e1 / se;
        out[4] = (o0 >= o1) ? 0.0f : 1.0f;
    }
}

// ---------------------------------------------------------------------------
extern "C" void kernel_launch(void* const* d_in, const int* in_sizes, int n_in,
                              void* d_out, int out_size, void* d_ws, size_t ws_size,
                              hipStream_t stream)
{
    const float* x      = (const float*)d_in[0];
    const float* fc1_w  = (const float*)d_in[1];
    const float* fc1_b  = (const float*)d_in[2];
    const float* wh_w   = (const float*)d_in[3];
    const float* wh_b   = (const float*)d_in[4];
    const float* wt_w   = (const float*)d_in[5];
    const float* wt_b   = (const float*)d_in[6];
    const float* lin1_w = (const float*)d_in[7];
    const float* lin1_b = (const float*)d_in[8];
    const float* lin2_w = (const float*)d_in[9];
    const float* lin2_b = (const float*)d_in[10];
    const float* att1_w = (const float*)d_in[11];
    const float* att1_b = (const float*)d_in[12];
    const float* att2_w = (const float*)d_in[13];
    const float* att2_b = (const float*)d_in[14];
    const float* ln_g   = (const float*)d_in[15];
    const float* ln_b   = (const float*)d_in[16];
    const float* fc_w   = (const float*)d_in[17];
    const float* fc_b   = (const float*)d_in[18];
    float* out = (float*)d_out;
    char* ws = (char*)d_ws;

    // Compact workspace layout (total 48 MB; small critical buffers first)
    u16*   fc1T   = (u16*)(ws + 0);          // 1,048,576
    u16*   whT    = (u16*)(ws + 1048576);    //   524,288
    u16*   wtT    = (u16*)(ws + 1572864);
    u16*   l1T    = (u16*)(ws + 2097152);
    u16*   l2T    = (u16*)(ws + 2621440);
    u16*   a1T    = (u16*)(ws + 3145728);    //   262,144
    float* tvp    = (float*)(ws + 3407872);  // 1,572,864
    int*   tip    = (int*)(ws + 4980736);    // 1,572,864
    float* tv     = (float*)(ws + 6553600);  //   196,608
    int*   ti     = (int*)(ws + 6750208);    //   196,608
    float* att    = (float*)(ws + 6946816);  //    32,768
    float* colsum = (float*)(ws + 6979584);  //     2,048
    float* pooled = (float*)(ws + 6981632);  //     2,048
    float* scal   = (float*)(ws + 6983680);  //        64
    u16*   hbf    = (u16*)(ws + 8388608);    // 8 MB  [h; later s1]
    u16*   ehbf   = (u16*)(ws + 16777216);   // 8 MB  [e_h bf16; later a1 fp32]
    u16*   etbf   = (u16*)(ws + 25165824);   // 8 MB  [e_t bf16]
    u16*   s2bf   = (u16*)(ws + 33554432);   // 8 MB  [s2]
    u16*   sebf   = (u16*)(ws + 41943040);   // 8 MB  [sum_e -> emb in place]
    float* a1f    = (float*)(ws + 16777216); // 8 MB fp32, reuses ehbf slot

    dim3 tb(32, 8);
    transpose_bf<<<dim3(16, 32), tb, 0, stream>>>(fc1_w, fc1T, 1024, 512);
    transpose_bf<<<dim3(16, 16), tb, 0, stream>>>(wh_w,  whT, 512, 512);
    transpose_bf<<<dim3(16, 16), tb, 0, stream>>>(wt_w,  wtT, 512, 512);
    transpose_bf<<<dim3(16, 16), tb, 0, stream>>>(lin1_w, l1T, 512, 512);
    transpose_bf<<<dim3(16, 16), tb, 0, stream>>>(lin2_w, l2T, 512, 512);
    transpose_bf<<<dim3(8, 16),  tb, 0, stream>>>(att1_w, a1T, 512, 256);

    // h = relu(x @ fc1_w + b)  -> bf16   (A = x in fp32)
    gemm_nt<1, 0, 0, 1><<<dim3(4, 64), 256, 0, stream>>>(x, fc1T, fc1_b, nullptr, hbf,
                                                         8192, 512, 1024);
    hipMemsetAsync(colsum, 0, 2048, stream);
    colsum_kernel<<<32, 256, 0, stream>>>(hbf, colsum);
    meanmix_kernel<<<16384, 256, 0, stream>>>(hbf, colsum);

    // e_h, e_t (bf16)
    gemm_nt<0, 0, 0, 0><<<dim3(4, 64), 256, 0, stream>>>(hbf, whT, wh_b, nullptr, ehbf,
                                                         8192, 512, 512);
    gemm_nt<0, 0, 0, 0><<<dim3(4, 64), 256, 0, stream>>>(hbf, wtT, wt_b, nullptr, etbf,
                                                         8192, 512, 512);

    // fused logits + top-6
    logits_topk<<<dim3(8, 64), 256, 0, stream>>>(ehbf, etbf, tvp, tip);
    topk_merge<<<32, 256, 0, stream>>>(tvp, tip, tv, ti);

    // per-row neighbor aggregation -> s1 (hbf), s2 (s2bf)
    neighbor_kernel<<<8192, 256, 0, stream>>>(ehbf, etbf, tv, ti, hbf, s2bf);

    // sum_e = lrelu(s1@lin1+b) -> sebf; emb = sum_e + lrelu(s2@lin2+b) in place
    gemm_nt<2, 0, 0, 0><<<dim3(4, 64), 256, 0, stream>>>(hbf, l1T, lin1_b, nullptr, sebf,
                                                         8192, 512, 512);
    gemm_nt<2, 1, 0, 0><<<dim3(4, 64), 256, 0, stream>>>(s2bf, l2T, lin2_b, nullptr, sebf,
                                                         8192, 512, 512);

    // att path: a1 = lrelu(emb @ att1 + b) fp32 (reuses ehbf slot)
    gemm_nt<2, 0, 1, 0><<<dim3(2, 64), 256, 0, stream>>>(sebf, a1T, att1_b, a1f, nullptr,
                                                         8192, 256, 512);
    att2_kernel<<<2048, 256, 0, stream>>>(a1f, att2_w, att2_b, att);
    att_prep<<<1, 256, 0, stream>>>(att, scal);
    hipMemsetAsync(pooled, 0, 2048, stream);
    pooled_kernel<<<32, 256, 0, stream>>>(sebf, att, scal, pooled);

    final_kernel<<<1, 256, 0, stream>>>(pooled, ln_g, ln_b, fc_w, fc_b, out);
}

// Round 4
// 576.488 us; speedup vs baseline: 1.3640x; 1.3640x over previous
//
#include <hip/hip_runtime.h>
#include <hip/hip_bf16.h>
#include <cstdint>
#include <math.h>

typedef unsigned short u16;
typedef __bf16 bh;
typedef bh bh8 __attribute__((ext_vector_type(8)));
typedef float f32x4 __attribute__((ext_vector_type(4)));

#define SCALE_F 0.04419417382415922f  // 512^-0.5

__device__ __forceinline__ float bf2f(u16 u) {
    union { float f; unsigned int i; } v; v.i = ((unsigned int)u) << 16; return v.f;
}
__device__ __forceinline__ u16 f2bf(float f) {
    __hip_bfloat16 h = __float2bfloat16(f);
    return __builtin_bit_cast(u16, h);
}

// load 8 contiguous fp32, round to bf16x8
__device__ __forceinline__ bh8 ld8_f32(const float* p) {
    float4 f0 = *(const float4*)p;
    float4 f1 = *(const float4*)(p + 4);
    bh8 r;
    r[0] = (bh)f0.x; r[1] = (bh)f0.y; r[2] = (bh)f0.z; r[3] = (bh)f0.w;
    r[4] = (bh)f1.x; r[5] = (bh)f1.y; r[6] = (bh)f1.z; r[7] = (bh)f1.w;
    return r;
}

// ---------------------------------------------------------------------------
// transpose + downcast: in fp32 [R, C] -> out bf16 [C, R]
__global__ void transpose_bf(const float* __restrict__ in, u16* __restrict__ out,
                             int R, int C) {
    __shared__ float t[32][33];
    int bx = blockIdx.x * 32, by = blockIdx.y * 32;
    int x = threadIdx.x, y = threadIdx.y;
    for (int i = 0; i < 32; i += 8)
        t[y + i][x] = in[(size_t)(by + y + i) * C + bx + x];
    __syncthreads();
    for (int i = 0; i < 32; i += 8)
        out[(size_t)(bx + y + i) * R + by + x] = f2bf(t[x][y + i]);
}

// ---------------------------------------------------------------------------
// NT GEMM: out[M,N] = act(A[M,K] @ B[N,K]^T + bias) (+ prior bf16 C if ADD).
// A bf16 (AF32=0) or fp32 (AF32=1) row-major; B bf16 row-major (pre-transposed).
// bias fp32. F32OUT: write fp32 to C, else bf16 to Cbf.
// ACT: 0 none, 1 relu, 2 leaky_relu(0.01). M%128==0, N%128==0, K%32==0.
template<int ACT, int ADD, int F32OUT, int AF32>
__global__ __launch_bounds__(256) void gemm_nt(
    const void* __restrict__ Av, const u16* __restrict__ B,
    const float* __restrict__ bias, float* __restrict__ C,
    u16* __restrict__ Cbf, int M, int N, int K)
{
    __shared__ __align__(16) u16 Alds[128 * 40];
    __shared__ __align__(16) u16 Blds[128 * 40];
    const int tid = threadIdx.x;
    const int m0 = blockIdx.y * 128, n0 = blockIdx.x * 128;
    const int lane = tid & 63, wave = tid >> 6;
    const int wm = (wave & 1) * 64, wn = (wave >> 1) * 64;
    const int lr = lane & 15, quad = lane >> 4;
    const int r0 = tid >> 2, k8 = (tid & 3) * 8;
    const int r1 = r0 + 64;

    const u16*   Ab = (const u16*)Av;
    const float* Af = (const float*)Av;
    const u16* Arow0b = Ab + (size_t)(m0 + r0) * K + k8;
    const u16* Arow1b = Ab + (size_t)(m0 + r1) * K + k8;
    const float* Arow0f = Af + (size_t)(m0 + r0) * K + k8;
    const float* Arow1f = Af + (size_t)(m0 + r1) * K + k8;
    const u16* Brow0 = B + (size_t)(n0 + r0) * K + k8;
    const u16* Brow1 = B + (size_t)(n0 + r1) * K + k8;

    f32x4 acc[4][4] = {};
    bh8 pa0, pa1, pb0, pb1;
    if (AF32) { pa0 = ld8_f32(Arow0f); pa1 = ld8_f32(Arow1f); }
    else      { pa0 = *(const bh8*)Arow0b; pa1 = *(const bh8*)Arow1b; }
    pb0 = *(const bh8*)Brow0;
    pb1 = *(const bh8*)Brow1;

    for (int k0 = 0; k0 < K; k0 += 32) {
        __syncthreads();
        *(bh8*)&Alds[r0 * 40 + k8] = pa0;
        *(bh8*)&Alds[r1 * 40 + k8] = pa1;
        *(bh8*)&Blds[r0 * 40 + k8] = pb0;
        *(bh8*)&Blds[r1 * 40 + k8] = pb1;
        __syncthreads();
        if (k0 + 32 < K) {
            if (AF32) { pa0 = ld8_f32(Arow0f + k0 + 32); pa1 = ld8_f32(Arow1f + k0 + 32); }
            else      { pa0 = *(const bh8*)(Arow0b + k0 + 32); pa1 = *(const bh8*)(Arow1b + k0 + 32); }
            pb0 = *(const bh8*)(Brow0 + k0 + 32);
            pb1 = *(const bh8*)(Brow1 + k0 + 32);
        }
        bh8 af[4], bfr[4];
        #pragma unroll
        for (int i = 0; i < 4; i++) {
            af[i]  = *(const bh8*)&Alds[(wm + i * 16 + lr) * 40 + quad * 8];
            bfr[i] = *(const bh8*)&Blds[(wn + i * 16 + lr) * 40 + quad * 8];
        }
        #pragma unroll
        for (int mi = 0; mi < 4; mi++)
            #pragma unroll
            for (int ni = 0; ni < 4; ni++)
                acc[mi][ni] = __builtin_amdgcn_mfma_f32_16x16x32_bf16(
                    af[mi], bfr[ni], acc[mi][ni], 0, 0, 0);
    }

    #pragma unroll
    for (int ni = 0; ni < 4; ni++) {
        int col = n0 + wn + ni * 16 + lr;
        float bs = bias[col];
        #pragma unroll
        for (int mi = 0; mi < 4; mi++) {
            #pragma unroll
            for (int i = 0; i < 4; i++) {
                int row = m0 + wm + mi * 16 + quad * 4 + i;
                float v = acc[mi][ni][i] + bs;
                if (ACT == 1) v = fmaxf(v, 0.0f);
                if (ACT == 2) v = (v > 0.0f) ? v : 0.01f * v;
                size_t o = (size_t)row * N + col;
                if (ADD) v += bf2f(Cbf[o]);
                if (F32OUT) C[o] = v;
                else        Cbf[o] = f2bf(v);
            }
        }
    }
}

// ---------------------------------------------------------------------------
// Fused logits GEMM + per-row running top-6 over a 1024-column chunk.
// Top-6 lists live in REGISTERS of the 128 scanning threads (one per row);
// common case per column = 1 LDS read + 1 register compare. Scale deferred
// to writeout (monotone, order-preserving).
__global__ __launch_bounds__(256) void logits_topk(
    const u16* __restrict__ Ah, const u16* __restrict__ Bt,
    float* __restrict__ tvp, int* __restrict__ tip)
{
    const int K = 512;
    __shared__ __align__(16) u16 Alds[128 * 40];
    __shared__ __align__(16) u16 Blds[128 * 40];
    __shared__ float S[128 * 65];
    const int tid = threadIdx.x;
    const int m0 = blockIdx.y * 128;
    const int chunk = blockIdx.x;          // 0..7, 1024 cols each
    const int lane = tid & 63, wave = tid >> 6;
    const int wm = (wave & 1) * 64, wn = (wave >> 1) * 64;
    const int lr = lane & 15, quad = lane >> 4;
    const int r0 = tid >> 2, k8 = (tid & 3) * 8;
    const int r1 = r0 + 64;

    float tvr[6]; int tir[6];
    #pragma unroll
    for (int j = 0; j < 6; j++) { tvr[j] = -INFINITY; tir[j] = 0; }

    const u16* Arow0 = Ah + (size_t)(m0 + r0) * K + k8;
    const u16* Arow1 = Ah + (size_t)(m0 + r1) * K + k8;

    for (int nt = 0; nt < 8; nt++) {
        int n0 = chunk * 1024 + nt * 128;
        const u16* Brow0 = Bt + (size_t)(n0 + r0) * K + k8;
        const u16* Brow1 = Bt + (size_t)(n0 + r1) * K + k8;
        f32x4 acc[4][4] = {};
        bh8 pa0 = *(const bh8*)(Arow0);
        bh8 pa1 = *(const bh8*)(Arow1);
        bh8 pb0 = *(const bh8*)(Brow0);
        bh8 pb1 = *(const bh8*)(Brow1);
        for (int k0 = 0; k0 < K; k0 += 32) {
            __syncthreads();
            *(bh8*)&Alds[r0 * 40 + k8] = pa0;
            *(bh8*)&Alds[r1 * 40 + k8] = pa1;
            *(bh8*)&Blds[r0 * 40 + k8] = pb0;
            *(bh8*)&Blds[r1 * 40 + k8] = pb1;
            __syncthreads();
            if (k0 + 32 < K) {
                pa0 = *(const bh8*)(Arow0 + k0 + 32);
                pa1 = *(const bh8*)(Arow1 + k0 + 32);
                pb0 = *(const bh8*)(Brow0 + k0 + 32);
                pb1 = *(const bh8*)(Brow1 + k0 + 32);
            }
            bh8 af[4], bfr[4];
            #pragma unroll
            for (int i = 0; i < 4; i++) {
                af[i]  = *(const bh8*)&Alds[(wm + i * 16 + lr) * 40 + quad * 8];
                bfr[i] = *(const bh8*)&Blds[(wn + i * 16 + lr) * 40 + quad * 8];
            }
            #pragma unroll
            for (int mi = 0; mi < 4; mi++)
                #pragma unroll
                for (int ni = 0; ni < 4; ni++)
                    acc[mi][ni] = __builtin_amdgcn_mfma_f32_16x16x32_bf16(
                        af[mi], bfr[ni], acc[mi][ni], 0, 0, 0);
        }
        // stage 64-col halves to LDS, scan with register-resident top-6
        for (int half = 0; half < 2; half++) {
            __syncthreads();
            if ((wave >> 1) == half) {
                #pragma unroll
                for (int mi = 0; mi < 4; mi++)
                    #pragma unroll
                    for (int ni = 0; ni < 4; ni++)
                        #pragma unroll
                        for (int i = 0; i < 4; i++)
                            S[(wm + mi * 16 + quad * 4 + i) * 65 + ni * 16 + lr]
                                = acc[mi][ni][i];
            }
            __syncthreads();
            if (tid < 128) {
                const float* Sr = &S[tid * 65];
                int cb = n0 + half * 64;
                #pragma unroll 8
                for (int c = 0; c < 64; c++) {
                    float val = Sr[c];
                    if (val > tvr[5]) {
                        tvr[5] = val; tir[5] = cb + c;
                        #pragma unroll
                        for (int j = 5; j > 0; j--) {
                            if (tvr[j] > tvr[j - 1]) {
                                float tf = tvr[j]; tvr[j] = tvr[j - 1]; tvr[j - 1] = tf;
                                int   tx = tir[j]; tir[j] = tir[j - 1]; tir[j - 1] = tx;
                            }
                        }
                    }
                }
            }
        }
    }
    if (tid < 128) {
        #pragma unroll
        for (int j = 0; j < 6; j++) {
            tvp[(size_t)(m0 + tid) * 48 + chunk * 6 + j] = tvr[j] * SCALE_F;
            tip[(size_t)(m0 + tid) * 48 + chunk * 6 + j] = tir[j];
        }
    }
}

// Merge 8 partial top-6 lists per row -> final top-6.
__global__ void topk_merge(const float* __restrict__ tvp, const int* __restrict__ tip,
                           float* __restrict__ tv, int* __restrict__ ti)
{
    int r = blockIdx.x * 256 + threadIdx.x;
    float v[6]; int ix[6];
    #pragma unroll
    for (int j = 0; j < 6; j++) { v[j] = -INFINITY; ix[j] = 0; }
    const float* pv = tvp + (size_t)r * 48;
    const int*   pi = tip + (size_t)r * 48;
    for (int c = 0; c < 48; c++) {
        float val = pv[c]; int id = pi[c];
        if (val > v[5]) {
            v[5] = val; ix[5] = id;
            #pragma unroll
            for (int j = 5; j > 0; j--) {
                if (v[j] > v[j - 1]) {
                    float tf = v[j]; v[j] = v[j - 1]; v[j - 1] = tf;
                    int   tx = ix[j]; ix[j] = ix[j - 1]; ix[j - 1] = tx;
                }
            }
        }
    }
    #pragma unroll
    for (int j = 0; j < 6; j++) { tv[(size_t)r * 6 + j] = v[j]; ti[(size_t)r * 6 + j] = ix[j]; }
}

// ---------------------------------------------------------------------------
// Per-row neighbor aggregation (bf16 inputs, fp32 math): p=softmax(tw);
// gate/ka/kp/e_Nh; emits s1 = bf16(e_h + e_Nh), s2 = bf16(e_h * e_Nh).
// Reductions via wave shuffles + one 24-float LDS exchange.
__global__ __launch_bounds__(256) void neighbor_kernel(
    const u16* __restrict__ eH, const u16* __restrict__ eT,
    const float* __restrict__ tv, const int* __restrict__ ti,
    u16* __restrict__ s1, u16* __restrict__ s2)
{
    __shared__ float part[24];
    const int n = blockIdx.x, tid = threadIdx.x;
    const int lane = tid & 63, wave = tid >> 6;
    float tw[6]; int id[6];
    #pragma unroll
    for (int j = 0; j < 6; j++) {
        tw[j] = tv[n * 6 + j];
        int t = ti[n * 6 + j];
        id[j] = ((unsigned)t < 8192u) ? t : 0;
    }
    float mx = tw[0];
    #pragma unroll
    for (int j = 1; j < 6; j++) mx = fmaxf(mx, tw[j]);
    float p[6]; float ps = 0.f;
    #pragma unroll
    for (int j = 0; j < 6; j++) { p[j] = __expf(tw[j] - mx); ps += p[j]; }
    float inv = 1.0f / ps;
    #pragma unroll
    for (int j = 0; j < 6; j++) p[j] *= inv;

    const size_t base = (size_t)n * 512;
    float eh0 = bf2f(eH[base + tid]), eh1 = bf2f(eH[base + tid + 256]);
    float nb0[6], nb1[6];
    #pragma unroll
    for (int j = 0; j < 6; j++) {
        size_t b = (size_t)id[j] * 512;
        nb0[j] = bf2f(eT[b + tid]); nb1[j] = bf2f(eT[b + tid + 256]);
    }
    #pragma unroll
    for (int j = 0; j < 6; j++) {
        float e0 = p[j] * nb0[j] + (1.f - p[j]) * eh0;
        float e1 = p[j] * nb1[j] + (1.f - p[j]) * eh1;
        float g0 = tanhf(eh0 + e0), g1 = tanhf(eh1 + e1);
        float s = nb0[j] * g0 + nb1[j] * g1;
        #pragma unroll
        for (int off = 32; off > 0; off >>= 1) s += __shfl_down(s, off);
        if (lane == 0) part[wave * 6 + j] = s;
    }
    __syncthreads();
    float ka[6];
    #pragma unroll
    for (int j = 0; j < 6; j++)
        ka[j] = part[j] + part[6 + j] + part[12 + j] + part[18 + j];
    float m2 = ka[0];
    #pragma unroll
    for (int j = 1; j < 6; j++) m2 = fmaxf(m2, ka[j]);
    float kp[6]; float ks = 0.f;
    #pragma unroll
    for (int j = 0; j < 6; j++) { kp[j] = __expf(ka[j] - m2); ks += kp[j]; }
    float inv2 = 1.0f / ks;
    #pragma unroll
    for (int j = 0; j < 6; j++) kp[j] *= inv2;
    float eN0 = 0.f, eN1 = 0.f;
    #pragma unroll
    for (int j = 0; j < 6; j++) { eN0 += kp[j] * nb0[j]; eN1 += kp[j] * nb1[j]; }
    s1[base + tid]       = f2bf(eh0 + eN0);
    s1[base + tid + 256] = f2bf(eh1 + eN1);
    s2[base + tid]       = f2bf(eh0 * eN0);
    s2[base + tid + 256] = f2bf(eh1 * eN1);
}

// ---------------------------------------------------------------------------
__global__ void colsum_kernel(const u16* __restrict__ h, float* __restrict__ colsum) {
    int tid = threadIdx.x;
    int n0 = blockIdx.x * 32;
    float a0 = 0.f, a1 = 0.f;
    for (int k = 0; k < 32; k++) {
        size_t b = (size_t)(n0 + k) * 512;
        a0 += bf2f(h[b + tid]); a1 += bf2f(h[b + tid + 256]);
    }
    atomicAdd(&colsum[tid], a0);
    atomicAdd(&colsum[tid + 256], a1);
}

__global__ void meanmix_kernel(u16* __restrict__ h, const float* __restrict__ colsum) {
    size_t i = ((size_t)blockIdx.x * 256 + threadIdx.x) * 8;
    int col = (int)(i & 511);
    union { int4 v; u16 s[8]; } u;
    u.v = *(const int4*)&h[i];
    #pragma unroll
    for (int j = 0; j < 8; j++)
        u.s[j] = f2bf((bf2f(u.s[j]) + colsum[col + j] * (1.0f / 8192.0f)) * 0.5f);
    *(int4*)&h[i] = u.v;
}

// att2: att[n] = dot(a1[n,:256], w) + b. One wave per row.
__global__ __launch_bounds__(256) void att2_kernel(
    const float* __restrict__ a1, const float* __restrict__ w,
    const float* __restrict__ b, float* __restrict__ att)
{
    int row = blockIdx.x * 4 + (threadIdx.x >> 6);
    int lane = threadIdx.x & 63;
    const float* pr = a1 + (size_t)row * 256;
    float s = 0.f;
    #pragma unroll
    for (int k = 0; k < 4; k++) { int c = lane + k * 64; s += pr[c] * w[c]; }
    #pragma unroll
    for (int off = 32; off > 0; off >>= 1) s += __shfl_down(s, off);
    if (lane == 0) att[row] = s + b[0];
}

__global__ void att_prep(const float* __restrict__ att, float* __restrict__ scal) {
    __shared__ float red[256];
    int tid = threadIdx.x;
    float mx = -INFINITY;
    for (int i = tid; i < 8192; i += 256) mx = fmaxf(mx, att[i]);
    red[tid] = mx; __syncthreads();
    for (int s = 128; s > 0; s >>= 1) {
        if (tid < s) red[tid] = fmaxf(red[tid], red[tid + s]);
        __syncthreads();
    }
    mx = red[0]; __syncthreads();
    float sm = 0.f;
    for (int i = tid; i < 8192; i += 256) sm += __expf(att[i] - mx);
    red[tid] = sm; __syncthreads();
    for (int s = 128; s > 0; s >>= 1) {
        if (tid < s) red[tid] += red[tid + s];
        __syncthreads();
    }
    if (tid == 0) { scal[0] = mx; scal[1] = red[0]; }
}

__global__ void pooled_kernel(const u16* __restrict__ emb, const float* __restrict__ att,
                              const float* __restrict__ scal, float* __restrict__ pooled) {
    int tid = threadIdx.x;
    int n0 = blockIdx.x * 32;
    float mx = scal[0]; float inv = 1.0f / scal[1];
    float a0 = 0.f, a1 = 0.f;
    for (int k = 0; k < 32; k++) {
        int n = n0 + k;
        float w = __expf(att[n] - mx) * inv;
        size_t b = (size_t)n * 512;
        a0 += w * bf2f(emb[b + tid]);
        a1 += w * bf2f(emb[b + tid + 256]);
    }
    atomicAdd(&pooled[tid], a0);
    atomicAdd(&pooled[tid + 256], a1);
}

__global__ void final_kernel(const float* __restrict__ pooled,
                             const float* __restrict__ g, const float* __restrict__ bln,
                             const float* __restrict__ fcw, const float* __restrict__ fcb,
                             float* __restrict__ out) {
    __shared__ float red[256];
    int tid = threadIdx.x;
    float x0 = pooled[tid], x1 = pooled[tid + 256];
    red[tid] = x0 + x1; __syncthreads();
    for (int s = 128; s > 0; s >>= 1) { if (tid < s) red[tid] += red[tid + s]; __syncthreads(); }
    float mu = red[0] * (1.0f / 512.0f); __syncthreads();
    float d0 = x0 - mu, d1 = x1 - mu;
    red[tid] = d0 * d0 + d1 * d1; __syncthreads();
    for (int s = 128; s > 0; s >>= 1) { if (tid < s) red[tid] += red[tid + s]; __syncthreads(); }
    float var = red[0] * (1.0f / 512.0f); __syncthreads();
    float rstd = rsqrtf(var + 1e-5f);
    float l0 = d0 * rstd * g[tid]       + bln[tid];
    float l1 = d1 * rstd * g[tid + 256] + bln[tid + 256];
    red[tid] = l0 * fcw[tid * 2] + l1 * fcw[(tid + 256) * 2]; __syncthreads();
    for (int s = 128; s > 0; s >>= 1) { if (tid < s) red[tid] += red[tid + s]; __syncthreads(); }
    float o0 = red[0] + fcb[0]; __syncthreads();
    red[tid] = l0 * fcw[tid * 2 + 1] + l1 * fcw[(tid + 256) * 2 + 1]; __syncthreads();
    for (int s = 128; s > 0; s >>= 1) { if (tid < s) red[tid] += red[tid + s]; __syncthreads(); }
    float o1 = red[0] + fcb[1];
    if (tid == 0) {
        float m = fmaxf(o0, o1);
        float e0 = expf(o0 - m), e1 = expf(o1 - m);
        float se = e0 + e1;
        out[0] = o0;
        out[1] = o1;
        out[2] = e0 / se;
        out[3] = e1 / se;
        out[4] = (o0 >= o1) ? 0.0f : 1.0f;
    }
}

// ---------------------------------------------------------------------------
extern "C" void kernel_launch(void* const* d_in, const int* in_sizes, int n_in,
                              void* d_out, int out_size, void* d_ws, size_t ws_size,
                              hipStream_t stream)
{
    const float* x      = (const float*)d_in[0];
    const float* fc1_w  = (const float*)d_in[1];
    const float* fc1_b  = (const float*)d_in[2];
    const float* wh_w   = (const float*)d_in[3];
    const float* wh_b   = (const float*)d_in[4];
    const float* wt_w   = (const float*)d_in[5];
    const float* wt_b   = (const float*)d_in[6];
    const float* lin1_w = (const float*)d_in[7];
    const float* lin1_b = (const float*)d_in[8];
    const float* lin2_w = (const float*)d_in[9];
    const float* lin2_b = (const float*)d_in[10];
    const float* att1_w = (const float*)d_in[11];
    const float* att1_b = (const float*)d_in[12];
    const float* att2_w = (const float*)d_in[13];
    const float* att2_b = (const float*)d_in[14];
    const float* ln_g   = (const float*)d_in[15];
    const float* ln_b   = (const float*)d_in[16];
    const float* fc_w   = (const float*)d_in[17];
    const float* fc_b   = (const float*)d_in[18];
    float* out = (float*)d_out;
    char* ws = (char*)d_ws;

    // Compact workspace layout (total 48 MB; small critical buffers first)
    u16*   fc1T   = (u16*)(ws + 0);          // 1,048,576
    u16*   whT    = (u16*)(ws + 1048576);    //   524,288
    u16*   wtT    = (u16*)(ws + 1572864);
    u16*   l1T    = (u16*)(ws + 2097152);
    u16*   l2T    = (u16*)(ws + 2621440);
    u16*   a1T    = (u16*)(ws + 3145728);    //   262,144
    float* tvp    = (float*)(ws + 3407872);  // 1,572,864
    int*   tip    = (int*)(ws + 4980736);    // 1,572,864
    float* tv     = (float*)(ws + 6553600);  //   196,608
    int*   ti     = (int*)(ws + 6750208);    //   196,608
    float* att    = (float*)(ws + 6946816);  //    32,768
    float* colsum = (float*)(ws + 6979584);  //     2,048
    float* pooled = (float*)(ws + 6981632);  //     2,048
    float* scal   = (float*)(ws + 6983680);  //        64
    u16*   hbf    = (u16*)(ws + 8388608);    // 8 MB  [h; later s1]
    u16*   ehbf   = (u16*)(ws + 16777216);   // 8 MB  [e_h bf16; later a1 fp32]
    u16*   etbf   = (u16*)(ws + 25165824);   // 8 MB  [e_t bf16]
    u16*   s2bf   = (u16*)(ws + 33554432);   // 8 MB  [s2]
    u16*   sebf   = (u16*)(ws + 41943040);   // 8 MB  [sum_e -> emb in place]
    float* a1f    = (float*)(ws + 16777216); // 8 MB fp32, reuses ehbf slot

    dim3 tb(32, 8);
    transpose_bf<<<dim3(16, 32), tb, 0, stream>>>(fc1_w, fc1T, 1024, 512);
    transpose_bf<<<dim3(16, 16), tb, 0, stream>>>(wh_w,  whT, 512, 512);
    transpose_bf<<<dim3(16, 16), tb, 0, stream>>>(wt_w,  wtT, 512, 512);
    transpose_bf<<<dim3(16, 16), tb, 0, stream>>>(lin1_w, l1T, 512, 512);
    transpose_bf<<<dim3(16, 16), tb, 0, stream>>>(lin2_w, l2T, 512, 512);
    transpose_bf<<<dim3(8, 16),  tb, 0, stream>>>(att1_w, a1T, 512, 256);

    // h = relu(x @ fc1_w + b)  -> bf16   (A = x in fp32)
    gemm_nt<1, 0, 0, 1><<<dim3(4, 64), 256, 0, stream>>>(x, fc1T, fc1_b, nullptr, hbf,
                                                         8192, 512, 1024);
    hipMemsetAsync(colsum, 0, 2048, stream);
    colsum_kernel<<<256, 256, 0, stream>>>(hbf, colsum);
    meanmix_kernel<<<2048, 256, 0, stream>>>(hbf, colsum);

    // e_h, e_t (bf16)
    gemm_nt<0, 0, 0, 0><<<dim3(4, 64), 256, 0, stream>>>(hbf, whT, wh_b, nullptr, ehbf,
                                                         8192, 512, 512);
    gemm_nt<0, 0, 0, 0><<<dim3(4, 64), 256, 0, stream>>>(hbf, wtT, wt_b, nullptr, etbf,
                                                         8192, 512, 512);

    // fused logits + top-6
    logits_topk<<<dim3(8, 64), 256, 0, stream>>>(ehbf, etbf, tvp, tip);
    topk_merge<<<32, 256, 0, stream>>>(tvp, tip, tv, ti);

    // per-row neighbor aggregation -> s1 (hbf), s2 (s2bf)
    neighbor_kernel<<<8192, 256, 0, stream>>>(ehbf, etbf, tv, ti, hbf, s2bf);

    // sum_e = lrelu(s1@lin1+b) -> sebf; emb = sum_e + lrelu(s2@lin2+b) in place
    gemm_nt<2, 0, 0, 0><<<dim3(4, 64), 256, 0, stream>>>(hbf, l1T, lin1_b, nullptr, sebf,
                                                         8192, 512, 512);
    gemm_nt<2, 1, 0, 0><<<dim3(4, 64), 256, 0, stream>>>(s2bf, l2T, lin2_b, nullptr, sebf,
                                                         8192, 512, 512);

    // att path: a1 = lrelu(emb @ att1 + b) fp32 (reuses ehbf slot)
    gemm_nt<2, 0, 1, 0><<<dim3(2, 64), 256, 0, stream>>>(sebf, a1T, att1_b, a1f, nullptr,
                                                         8192, 256, 512);
    att2_kernel<<<2048, 256, 0, stream>>>(a1f, att2_w, att2_b, att);
    att_prep<<<1, 256, 0, stream>>>(att, scal);
    hipMemsetAsync(pooled, 0, 2048, stream);
    pooled_kernel<<<256, 256, 0, stream>>>(sebf, att, scal, pooled);

    final_kernel<<<1, 256, 0, stream>>>(pooled, ln_g, ln_b, fc_w, fc_b, out);
}

// Round 5
// 566.509 us; speedup vs baseline: 1.3880x; 1.0176x over previous
//
#include <hip/hip_runtime.h>
#include <hip/hip_bf16.h>
#include <cstdint>
#include <math.h>

typedef unsigned short u16;
typedef __bf16 bh;
typedef bh bh8 __attribute__((ext_vector_type(8)));
typedef float f32x4 __attribute__((ext_vector_type(4)));

#define SCALE_F 0.04419417382415922f  // 512^-0.5

__device__ __forceinline__ float bf2f(u16 u) {
    union { float f; unsigned int i; } v; v.i = ((unsigned int)u) << 16; return v.f;
}
__device__ __forceinline__ u16 f2bf(float f) {
    __hip_bfloat16 h = __float2bfloat16(f);
    return __builtin_bit_cast(u16, h);
}

// load 8 contiguous fp32, round to bf16x8
__device__ __forceinline__ bh8 ld8_f32(const float* p) {
    float4 f0 = *(const float4*)p;
    float4 f1 = *(const float4*)(p + 4);
    bh8 r;
    r[0] = (bh)f0.x; r[1] = (bh)f0.y; r[2] = (bh)f0.z; r[3] = (bh)f0.w;
    r[4] = (bh)f1.x; r[5] = (bh)f1.y; r[6] = (bh)f1.z; r[7] = (bh)f1.w;
    return r;
}

// ---------------------------------------------------------------------------
// transpose + downcast: in fp32 [R, C] -> out bf16 [C, R]
__global__ void transpose_bf(const float* __restrict__ in, u16* __restrict__ out,
                             int R, int C) {
    __shared__ float t[32][33];
    int bx = blockIdx.x * 32, by = blockIdx.y * 32;
    int x = threadIdx.x, y = threadIdx.y;
    for (int i = 0; i < 32; i += 8)
        t[y + i][x] = in[(size_t)(by + y + i) * C + bx + x];
    __syncthreads();
    for (int i = 0; i < 32; i += 8)
        out[(size_t)(bx + y + i) * R + by + x] = f2bf(t[x][y + i]);
}

// ---------------------------------------------------------------------------
// NT GEMM: out[M,N] = act(A[M,K] @ B[N,K]^T + bias) (+ prior bf16 C if ADD).
// A bf16 (AF32=0) or fp32 (AF32=1) row-major; B bf16 row-major (pre-transposed).
// bias fp32. F32OUT: write fp32 to C, else bf16 to Cbf.
// ACT: 0 none, 1 relu, 2 leaky_relu(0.01). M%128==0, N%128==0, K%32==0.
template<int ACT, int ADD, int F32OUT, int AF32>
__global__ __launch_bounds__(256) void gemm_nt(
    const void* __restrict__ Av, const u16* __restrict__ B,
    const float* __restrict__ bias, float* __restrict__ C,
    u16* __restrict__ Cbf, int M, int N, int K)
{
    __shared__ __align__(16) u16 Alds[128 * 40];
    __shared__ __align__(16) u16 Blds[128 * 40];
    const int tid = threadIdx.x;
    const int m0 = blockIdx.y * 128, n0 = blockIdx.x * 128;
    const int lane = tid & 63, wave = tid >> 6;
    const int wm = (wave & 1) * 64, wn = (wave >> 1) * 64;
    const int lr = lane & 15, quad = lane >> 4;
    const int r0 = tid >> 2, k8 = (tid & 3) * 8;
    const int r1 = r0 + 64;

    const u16*   Ab = (const u16*)Av;
    const float* Af = (const float*)Av;
    const u16* Arow0b = Ab + (size_t)(m0 + r0) * K + k8;
    const u16* Arow1b = Ab + (size_t)(m0 + r1) * K + k8;
    const float* Arow0f = Af + (size_t)(m0 + r0) * K + k8;
    const float* Arow1f = Af + (size_t)(m0 + r1) * K + k8;
    const u16* Brow0 = B + (size_t)(n0 + r0) * K + k8;
    const u16* Brow1 = B + (size_t)(n0 + r1) * K + k8;

    f32x4 acc[4][4] = {};
    bh8 pa0, pa1, pb0, pb1;
    if (AF32) { pa0 = ld8_f32(Arow0f); pa1 = ld8_f32(Arow1f); }
    else      { pa0 = *(const bh8*)Arow0b; pa1 = *(const bh8*)Arow1b; }
    pb0 = *(const bh8*)Brow0;
    pb1 = *(const bh8*)Brow1;

    for (int k0 = 0; k0 < K; k0 += 32) {
        __syncthreads();
        *(bh8*)&Alds[r0 * 40 + k8] = pa0;
        *(bh8*)&Alds[r1 * 40 + k8] = pa1;
        *(bh8*)&Blds[r0 * 40 + k8] = pb0;
        *(bh8*)&Blds[r1 * 40 + k8] = pb1;
        __syncthreads();
        if (k0 + 32 < K) {
            if (AF32) { pa0 = ld8_f32(Arow0f + k0 + 32); pa1 = ld8_f32(Arow1f + k0 + 32); }
            else      { pa0 = *(const bh8*)(Arow0b + k0 + 32); pa1 = *(const bh8*)(Arow1b + k0 + 32); }
            pb0 = *(const bh8*)(Brow0 + k0 + 32);
            pb1 = *(const bh8*)(Brow1 + k0 + 32);
        }
        bh8 af[4], bfr[4];
        #pragma unroll
        for (int i = 0; i < 4; i++) {
            af[i]  = *(const bh8*)&Alds[(wm + i * 16 + lr) * 40 + quad * 8];
            bfr[i] = *(const bh8*)&Blds[(wn + i * 16 + lr) * 40 + quad * 8];
        }
        #pragma unroll
        for (int mi = 0; mi < 4; mi++)
            #pragma unroll
            for (int ni = 0; ni < 4; ni++)
                acc[mi][ni] = __builtin_amdgcn_mfma_f32_16x16x32_bf16(
                    af[mi], bfr[ni], acc[mi][ni], 0, 0, 0);
    }

    #pragma unroll
    for (int ni = 0; ni < 4; ni++) {
        int col = n0 + wn + ni * 16 + lr;
        float bs = bias[col];
        #pragma unroll
        for (int mi = 0; mi < 4; mi++) {
            #pragma unroll
            for (int i = 0; i < 4; i++) {
                int row = m0 + wm + mi * 16 + quad * 4 + i;
                float v = acc[mi][ni][i] + bs;
                if (ACT == 1) v = fmaxf(v, 0.0f);
                if (ACT == 2) v = (v > 0.0f) ? v : 0.01f * v;
                size_t o = (size_t)row * N + col;
                if (ADD) v += bf2f(Cbf[o]);
                if (F32OUT) C[o] = v;
                else        Cbf[o] = f2bf(v);
            }
        }
    }
}

// ---------------------------------------------------------------------------
// Fused logits GEMM + per-row running top-6 over a 256-column span.
// Grid (32, 64): block = 128 rows x 256 cols (2 x 128-col tiles).
// All 256 threads scan: row = tid>>1, 32 cols per half-tile. Per-thread
// register top-6; pairwise merge through LDS with index tie-break
// (preserves lax.top_k tie semantics). Scale deferred to writeout.
__global__ __launch_bounds__(256) void logits_topk(
    const u16* __restrict__ Ah, const u16* __restrict__ Bt,
    float* __restrict__ tvp, u16* __restrict__ tip)
{
    const int K = 512;
    __shared__ __align__(16) u16 Alds[128 * 40];
    __shared__ __align__(16) u16 Blds[128 * 40];
    __shared__ float S[128 * 65];
    const int tid = threadIdx.x;
    const int m0 = blockIdx.y * 128;
    const int cb0 = blockIdx.x * 256;      // 256-col span
    const int lane = tid & 63, wave = tid >> 6;
    const int wm = (wave & 1) * 64, wn = (wave >> 1) * 64;
    const int lr = lane & 15, quad = lane >> 4;
    const int r0 = tid >> 2, k8 = (tid & 3) * 8;
    const int r1 = r0 + 64;
    const int srow = tid >> 1, scg = tid & 1;   // scan row / column-group

    float tvr[6]; int tir[6];
    #pragma unroll
    for (int j = 0; j < 6; j++) { tvr[j] = -INFINITY; tir[j] = 0; }

    const u16* Arow0 = Ah + (size_t)(m0 + r0) * K + k8;
    const u16* Arow1 = Ah + (size_t)(m0 + r1) * K + k8;

    for (int nt = 0; nt < 2; nt++) {
        int n0 = cb0 + nt * 128;
        const u16* Brow0 = Bt + (size_t)(n0 + r0) * K + k8;
        const u16* Brow1 = Bt + (size_t)(n0 + r1) * K + k8;
        f32x4 acc[4][4] = {};
        bh8 pa0 = *(const bh8*)(Arow0);
        bh8 pa1 = *(const bh8*)(Arow1);
        bh8 pb0 = *(const bh8*)(Brow0);
        bh8 pb1 = *(const bh8*)(Brow1);
        for (int k0 = 0; k0 < K; k0 += 32) {
            __syncthreads();
            *(bh8*)&Alds[r0 * 40 + k8] = pa0;
            *(bh8*)&Alds[r1 * 40 + k8] = pa1;
            *(bh8*)&Blds[r0 * 40 + k8] = pb0;
            *(bh8*)&Blds[r1 * 40 + k8] = pb1;
            __syncthreads();
            if (k0 + 32 < K) {
                pa0 = *(const bh8*)(Arow0 + k0 + 32);
                pa1 = *(const bh8*)(Arow1 + k0 + 32);
                pb0 = *(const bh8*)(Brow0 + k0 + 32);
                pb1 = *(const bh8*)(Brow1 + k0 + 32);
            }
            bh8 af[4], bfr[4];
            #pragma unroll
            for (int i = 0; i < 4; i++) {
                af[i]  = *(const bh8*)&Alds[(wm + i * 16 + lr) * 40 + quad * 8];
                bfr[i] = *(const bh8*)&Blds[(wn + i * 16 + lr) * 40 + quad * 8];
            }
            #pragma unroll
            for (int mi = 0; mi < 4; mi++)
                #pragma unroll
                for (int ni = 0; ni < 4; ni++)
                    acc[mi][ni] = __builtin_amdgcn_mfma_f32_16x16x32_bf16(
                        af[mi], bfr[ni], acc[mi][ni], 0, 0, 0);
        }
        // stage 64-col halves to LDS, scan with all 256 threads
        for (int half = 0; half < 2; half++) {
            __syncthreads();
            if ((wave >> 1) == half) {
                #pragma unroll
                for (int mi = 0; mi < 4; mi++)
                    #pragma unroll
                    for (int ni = 0; ni < 4; ni++)
                        #pragma unroll
                        for (int i = 0; i < 4; i++)
                            S[(wm + mi * 16 + quad * 4 + i) * 65 + ni * 16 + lr]
                                = acc[mi][ni][i];
            }
            __syncthreads();
            {
                const float* Sr = &S[srow * 65 + scg * 32];
                int cb = n0 + half * 64 + scg * 32;
                #pragma unroll 8
                for (int c = 0; c < 32; c++) {
                    float val = Sr[c];
                    if (val > tvr[5]) {
                        tvr[5] = val; tir[5] = cb + c;
                        #pragma unroll
                        for (int j = 5; j > 0; j--) {
                            if (tvr[j] > tvr[j - 1]) {
                                float tf = tvr[j]; tvr[j] = tvr[j - 1]; tvr[j - 1] = tf;
                                int   tx = tir[j]; tir[j] = tir[j - 1]; tir[j - 1] = tx;
                            }
                        }
                    }
                }
            }
        }
    }
    // merge the two column-group lists per row through LDS (idx tie-break)
    __syncthreads();
    #pragma unroll
    for (int j = 0; j < 6; j++) {
        S[srow * 65 + scg * 6 + j]      = tvr[j];
        S[srow * 65 + 12 + scg * 6 + j] = __int_as_float(tir[j]);
    }
    __syncthreads();
    if (tid < 128) {
        float mv[6]; int mi[6];
        #pragma unroll
        for (int j = 0; j < 6; j++) { mv[j] = -INFINITY; mi[j] = 0; }
        const float* Sr = &S[tid * 65];
        #pragma unroll
        for (int s = 0; s < 12; s++) {
            float val = Sr[s];
            int   id  = __float_as_int(Sr[12 + s]);
            if (val > mv[5] || (val == mv[5] && id < mi[5])) {
                mv[5] = val; mi[5] = id;
                #pragma unroll
                for (int j = 5; j > 0; j--) {
                    if (mv[j] > mv[j - 1] || (mv[j] == mv[j - 1] && mi[j] < mi[j - 1])) {
                        float tf = mv[j]; mv[j] = mv[j - 1]; mv[j - 1] = tf;
                        int   tx = mi[j]; mi[j] = mi[j - 1]; mi[j - 1] = tx;
                    }
                }
            }
        }
        size_t base = (size_t)(m0 + tid) * 192 + blockIdx.x * 6;
        #pragma unroll
        for (int j = 0; j < 6; j++) {
            tvp[base + j] = mv[j] * SCALE_F;
            tip[base + j] = (u16)mi[j];
        }
    }
}

// Merge 32 partial top-6 lists per row -> final top-6.
__global__ void topk_merge(const float* __restrict__ tvp, const u16* __restrict__ tip,
                           float* __restrict__ tv, int* __restrict__ ti)
{
    int r = blockIdx.x * 256 + threadIdx.x;
    float v[6]; int ix[6];
    #pragma unroll
    for (int j = 0; j < 6; j++) { v[j] = -INFINITY; ix[j] = 0; }
    const float* pv = tvp + (size_t)r * 192;
    const u16*   pi = tip + (size_t)r * 192;
    for (int c = 0; c < 192; c++) {
        float val = pv[c];
        if (val > v[5]) {
            v[5] = val; ix[5] = pi[c];
            #pragma unroll
            for (int j = 5; j > 0; j--) {
                if (v[j] > v[j - 1]) {
                    float tf = v[j]; v[j] = v[j - 1]; v[j - 1] = tf;
                    int   tx = ix[j]; ix[j] = ix[j - 1]; ix[j - 1] = tx;
                }
            }
        }
    }
    #pragma unroll
    for (int j = 0; j < 6; j++) { tv[(size_t)r * 6 + j] = v[j]; ti[(size_t)r * 6 + j] = ix[j]; }
}

// ---------------------------------------------------------------------------
// Per-row neighbor aggregation (bf16 inputs, fp32 math): p=softmax(tw);
// gate/ka/kp/e_Nh; emits s1 = bf16(e_h + e_Nh), s2 = bf16(e_h * e_Nh).
__global__ __launch_bounds__(256) void neighbor_kernel(
    const u16* __restrict__ eH, const u16* __restrict__ eT,
    const float* __restrict__ tv, const int* __restrict__ ti,
    u16* __restrict__ s1, u16* __restrict__ s2)
{
    __shared__ float part[24];
    const int n = blockIdx.x, tid = threadIdx.x;
    const int lane = tid & 63, wave = tid >> 6;
    float tw[6]; int id[6];
    #pragma unroll
    for (int j = 0; j < 6; j++) {
        tw[j] = tv[n * 6 + j];
        int t = ti[n * 6 + j];
        id[j] = ((unsigned)t < 8192u) ? t : 0;
    }
    float mx = tw[0];
    #pragma unroll
    for (int j = 1; j < 6; j++) mx = fmaxf(mx, tw[j]);
    float p[6]; float ps = 0.f;
    #pragma unroll
    for (int j = 0; j < 6; j++) { p[j] = __expf(tw[j] - mx); ps += p[j]; }
    float inv = 1.0f / ps;
    #pragma unroll
    for (int j = 0; j < 6; j++) p[j] *= inv;

    const size_t base = (size_t)n * 512;
    float eh0 = bf2f(eH[base + tid]), eh1 = bf2f(eH[base + tid + 256]);
    float nb0[6], nb1[6];
    #pragma unroll
    for (int j = 0; j < 6; j++) {
        size_t b = (size_t)id[j] * 512;
        nb0[j] = bf2f(eT[b + tid]); nb1[j] = bf2f(eT[b + tid + 256]);
    }
    #pragma unroll
    for (int j = 0; j < 6; j++) {
        float e0 = p[j] * nb0[j] + (1.f - p[j]) * eh0;
        float e1 = p[j] * nb1[j] + (1.f - p[j]) * eh1;
        float g0 = tanhf(eh0 + e0), g1 = tanhf(eh1 + e1);
        float s = nb0[j] * g0 + nb1[j] * g1;
        #pragma unroll
        for (int off = 32; off > 0; off >>= 1) s += __shfl_down(s, off);
        if (lane == 0) part[wave * 6 + j] = s;
    }
    __syncthreads();
    float ka[6];
    #pragma unroll
    for (int j = 0; j < 6; j++)
        ka[j] = part[j] + part[6 + j] + part[12 + j] + part[18 + j];
    float m2 = ka[0];
    #pragma unroll
    for (int j = 1; j < 6; j++) m2 = fmaxf(m2, ka[j]);
    float kp[6]; float ks = 0.f;
    #pragma unroll
    for (int j = 0; j < 6; j++) { kp[j] = __expf(ka[j] - m2); ks += kp[j]; }
    float inv2 = 1.0f / ks;
    #pragma unroll
    for (int j = 0; j < 6; j++) kp[j] *= inv2;
    float eN0 = 0.f, eN1 = 0.f;
    #pragma unroll
    for (int j = 0; j < 6; j++) { eN0 += kp[j] * nb0[j]; eN1 += kp[j] * nb1[j]; }
    s1[base + tid]       = f2bf(eh0 + eN0);
    s1[base + tid + 256] = f2bf(eh1 + eN1);
    s2[base + tid]       = f2bf(eh0 * eN0);
    s2[base + tid + 256] = f2bf(eh1 * eN1);
}

// ---------------------------------------------------------------------------
__global__ void colsum_kernel(const u16* __restrict__ h, float* __restrict__ colsum) {
    int tid = threadIdx.x;
    int n0 = blockIdx.x * 32;
    float a0 = 0.f, a1 = 0.f;
    for (int k = 0; k < 32; k++) {
        size_t b = (size_t)(n0 + k) * 512;
        a0 += bf2f(h[b + tid]); a1 += bf2f(h[b + tid + 256]);
    }
    atomicAdd(&colsum[tid], a0);
    atomicAdd(&colsum[tid + 256], a1);
}

__global__ void meanmix_kernel(u16* __restrict__ h, const float* __restrict__ colsum) {
    size_t i = ((size_t)blockIdx.x * 256 + threadIdx.x) * 8;
    int col = (int)(i & 511);
    union { int4 v; u16 s[8]; } u;
    u.v = *(const int4*)&h[i];
    #pragma unroll
    for (int j = 0; j < 8; j++)
        u.s[j] = f2bf((bf2f(u.s[j]) + colsum[col + j] * (1.0f / 8192.0f)) * 0.5f);
    *(int4*)&h[i] = u.v;
}

// att2: att[n] = dot(a1[n,:256], w) + b. One wave per row.
__global__ __launch_bounds__(256) void att2_kernel(
    const float* __restrict__ a1, const float* __restrict__ w,
    const float* __restrict__ b, float* __restrict__ att)
{
    int row = blockIdx.x * 4 + (threadIdx.x >> 6);
    int lane = threadIdx.x & 63;
    const float* pr = a1 + (size_t)row * 256;
    float s = 0.f;
    #pragma unroll
    for (int k = 0; k < 4; k++) { int c = lane + k * 64; s += pr[c] * w[c]; }
    #pragma unroll
    for (int off = 32; off > 0; off >>= 1) s += __shfl_down(s, off);
    if (lane == 0) att[row] = s + b[0];
}

__global__ void att_prep(const float* __restrict__ att, float* __restrict__ scal) {
    __shared__ float red[256];
    int tid = threadIdx.x;
    float mx = -INFINITY;
    for (int i = tid; i < 8192; i += 256) mx = fmaxf(mx, att[i]);
    red[tid] = mx; __syncthreads();
    for (int s = 128; s > 0; s >>= 1) {
        if (tid < s) red[tid] = fmaxf(red[tid], red[tid + s]);
        __syncthreads();
    }
    mx = red[0]; __syncthreads();
    float sm = 0.f;
    for (int i = tid; i < 8192; i += 256) sm += __expf(att[i] - mx);
    red[tid] = sm; __syncthreads();
    for (int s = 128; s > 0; s >>= 1) {
        if (tid < s) red[tid] += red[tid + s];
        __syncthreads();
    }
    if (tid == 0) { scal[0] = mx; scal[1] = red[0]; }
}

__global__ void pooled_kernel(const u16* __restrict__ emb, const float* __restrict__ att,
                              const float* __restrict__ scal, float* __restrict__ pooled) {
    int tid = threadIdx.x;
    int n0 = blockIdx.x * 32;
    float mx = scal[0]; float inv = 1.0f / scal[1];
    float a0 = 0.f, a1 = 0.f;
    for (int k = 0; k < 32; k++) {
        int n = n0 + k;
        float w = __expf(att[n] - mx) * inv;
        size_t b = (size_t)n * 512;
        a0 += w * bf2f(emb[b + tid]);
        a1 += w * bf2f(emb[b + tid + 256]);
    }
    atomicAdd(&pooled[tid], a0);
    atomicAdd(&pooled[tid + 256], a1);
}

__global__ void final_kernel(const float* __restrict__ pooled,
                             const float* __restrict__ g, const float* __restrict__ bln,
                             const float* __restrict__ fcw, const float* __restrict__ fcb,
                             float* __restrict__ out) {
    __shared__ float red[256];
    int tid = threadIdx.x;
    float x0 = pooled[tid], x1 = pooled[tid + 256];
    red[tid] = x0 + x1; __syncthreads();
    for (int s = 128; s > 0; s >>= 1) { if (tid < s) red[tid] += red[tid + s]; __syncthreads(); }
    float mu = red[0] * (1.0f / 512.0f); __syncthreads();
    float d0 = x0 - mu, d1 = x1 - mu;
    red[tid] = d0 * d0 + d1 * d1; __syncthreads();
    for (int s = 128; s > 0; s >>= 1) { if (tid < s) red[tid] += red[tid + s]; __syncthreads(); }
    float var = red[0] * (1.0f / 512.0f); __syncthreads();
    float rstd = rsqrtf(var + 1e-5f);
    float l0 = d0 * rstd * g[tid]       + bln[tid];
    float l1 = d1 * rstd * g[tid + 256] + bln[tid + 256];
    red[tid] = l0 * fcw[tid * 2] + l1 * fcw[(tid + 256) * 2]; __syncthreads();
    for (int s = 128; s > 0; s >>= 1) { if (tid < s) red[tid] += red[tid + s]; __syncthreads(); }
    float o0 = red[0] + fcb[0]; __syncthreads();
    red[tid] = l0 * fcw[tid * 2 + 1] + l1 * fcw[(tid + 256) * 2 + 1]; __syncthreads();
    for (int s = 128; s > 0; s >>= 1) { if (tid < s) red[tid] += red[tid + s]; __syncthreads(); }
    float o1 = red[0] + fcb[1];
    if (tid == 0) {
        float m = fmaxf(o0, o1);
        float e0 = expf(o0 - m), e1 = expf(o1 - m);
        float se = e0 + e1;
        out[0] = o0;
        out[1] = o1;
        out[2] = e0 / se;
        out[3] = e1 / se;
        out[4] = (o0 >= o1) ? 0.0f : 1.0f;
    }
}

// ---------------------------------------------------------------------------
extern "C" void kernel_launch(void* const* d_in, const int* in_sizes, int n_in,
                              void* d_out, int out_size, void* d_ws, size_t ws_size,
                              hipStream_t stream)
{
    const float* x      = (const float*)d_in[0];
    const float* fc1_w  = (const float*)d_in[1];
    const float* fc1_b  = (const float*)d_in[2];
    const float* wh_w   = (const float*)d_in[3];
    const float* wh_b   = (const float*)d_in[4];
    const float* wt_w   = (const float*)d_in[5];
    const float* wt_b   = (const float*)d_in[6];
    const float* lin1_w = (const float*)d_in[7];
    const float* lin1_b = (const float*)d_in[8];
    const float* lin2_w = (const float*)d_in[9];
    const float* lin2_b = (const float*)d_in[10];
    const float* att1_w = (const float*)d_in[11];
    const float* att1_b = (const float*)d_in[12];
    const float* att2_w = (const float*)d_in[13];
    const float* att2_b = (const float*)d_in[14];
    const float* ln_g   = (const float*)d_in[15];
    const float* ln_b   = (const float*)d_in[16];
    const float* fc_w   = (const float*)d_in[17];
    const float* fc_b   = (const float*)d_in[18];
    float* out = (float*)d_out;
    char* ws = (char*)d_ws;

    // Workspace layout (≈46 MB total; ws≥48MB verified working in R3/R4)
    u16*   fc1T   = (u16*)(ws + 0);          // 1 MB
    u16*   whT    = (u16*)(ws + 1048576);
    u16*   wtT    = (u16*)(ws + 1572864);
    u16*   l1T    = (u16*)(ws + 2097152);
    u16*   l2T    = (u16*)(ws + 2621440);
    u16*   a1T    = (u16*)(ws + 3145728);
    float* tv     = (float*)(ws + 3407872);  // 196,608
    int*   ti     = (int*)(ws + 3604480);    // 196,608
    float* att    = (float*)(ws + 3801088);  // 32,768
    float* colsum = (float*)(ws + 3833856);  // 2,048
    float* pooled = (float*)(ws + 3835904);  // 2,048
    float* scal   = (float*)(ws + 3837952);  // 64
    float* tvp    = (float*)(ws + 4194304);  // 8192*192*4 = 6,291,456
    u16*   tip    = (u16*)(ws + 10485760);   // 8192*192*2 = 3,145,728
    u16*   hbf    = (u16*)(ws + 14680064);   // 8 MB  [h; later s1]
    u16*   ehbf   = (u16*)(ws + 23068672);   // 8 MB  [e_h; later a1 fp32]
    u16*   etbf   = (u16*)(ws + 31457280);   // 8 MB  [e_t; later sum_e/emb]
    u16*   s2bf   = (u16*)(ws + 39845888);   // 8 MB  [s2]  (ends 48,234,496)
    float* a1f    = (float*)(ws + 23068672); // 8 MB fp32, reuses ehbf slot

    dim3 tb(32, 8);
    transpose_bf<<<dim3(16, 32), tb, 0, stream>>>(fc1_w, fc1T, 1024, 512);
    transpose_bf<<<dim3(16, 16), tb, 0, stream>>>(wh_w,  whT, 512, 512);
    transpose_bf<<<dim3(16, 16), tb, 0, stream>>>(wt_w,  wtT, 512, 512);
    transpose_bf<<<dim3(16, 16), tb, 0, stream>>>(lin1_w, l1T, 512, 512);
    transpose_bf<<<dim3(16, 16), tb, 0, stream>>>(lin2_w, l2T, 512, 512);
    transpose_bf<<<dim3(8, 16),  tb, 0, stream>>>(att1_w, a1T, 512, 256);

    // h = relu(x @ fc1_w + b)  -> bf16   (A = x in fp32)
    gemm_nt<1, 0, 0, 1><<<dim3(4, 64), 256, 0, stream>>>(x, fc1T, fc1_b, nullptr, hbf,
                                                         8192, 512, 1024);
    hipMemsetAsync(colsum, 0, 2048, stream);
    colsum_kernel<<<256, 256, 0, stream>>>(hbf, colsum);
    meanmix_kernel<<<2048, 256, 0, stream>>>(hbf, colsum);

    // e_h, e_t (bf16)
    gemm_nt<0, 0, 0, 0><<<dim3(4, 64), 256, 0, stream>>>(hbf, whT, wh_b, nullptr, ehbf,
                                                         8192, 512, 512);
    gemm_nt<0, 0, 0, 0><<<dim3(4, 64), 256, 0, stream>>>(hbf, wtT, wt_b, nullptr, etbf,
                                                         8192, 512, 512);

    // fused logits + top-6 (2048 blocks)
    logits_topk<<<dim3(32, 64), 256, 0, stream>>>(ehbf, etbf, tvp, tip);
    topk_merge<<<32, 256, 0, stream>>>(tvp, tip, tv, ti);

    // per-row neighbor aggregation -> s1 (hbf), s2 (s2bf)
    neighbor_kernel<<<8192, 256, 0, stream>>>(ehbf, etbf, tv, ti, hbf, s2bf);

    // sum_e = lrelu(s1@lin1+b) -> etbf; emb = sum_e + lrelu(s2@lin2+b) in place
    gemm_nt<2, 0, 0, 0><<<dim3(4, 64), 256, 0, stream>>>(hbf, l1T, lin1_b, nullptr, etbf,
                                                         8192, 512, 512);
    gemm_nt<2, 1, 0, 0><<<dim3(4, 64), 256, 0, stream>>>(s2bf, l2T, lin2_b, nullptr, etbf,
                                                         8192, 512, 512);

    // att path: a1 = lrelu(emb @ att1 + b) fp32 (reuses ehbf slot)
    gemm_nt<2, 0, 1, 0><<<dim3(2, 64), 256, 0, stream>>>(etbf, a1T, att1_b, a1f, nullptr,
                                                         8192, 256, 512);
    att2_kernel<<<2048, 256, 0, stream>>>(a1f, att2_w, att2_b, att);
    att_prep<<<1, 256, 0, stream>>>(att, scal);
    hipMemsetAsync(pooled, 0, 2048, stream);
    pooled_kernel<<<256, 256, 0, stream>>>(etbf, att, scal, pooled);

    final_kernel<<<1, 256, 0, stream>>>(pooled, ln_g, ln_b, fc_w, fc_b, out);
}

// Round 6
// 473.573 us; speedup vs baseline: 1.6604x; 1.1962x over previous
//
#include <hip/hip_runtime.h>
#include <hip/hip_bf16.h>
#include <cstdint>
#include <math.h>

typedef unsigned short u16;
typedef unsigned int u32;
typedef __bf16 bh;
typedef bh bh8 __attribute__((ext_vector_type(8)));
typedef float f32x4 __attribute__((ext_vector_type(4)));

#define SCALE_F 0.04419417382415922f  // 512^-0.5

__device__ __forceinline__ float bf2f(u16 u) {
    union { float f; unsigned int i; } v; v.i = ((unsigned int)u) << 16; return v.f;
}
__device__ __forceinline__ u16 f2bf(float f) {
    __hip_bfloat16 h = __float2bfloat16(f);
    return __builtin_bit_cast(u16, h);
}
__device__ __forceinline__ bh8 ld8_f32(const float* p) {
    float4 f0 = *(const float4*)p;
    float4 f1 = *(const float4*)(p + 4);
    bh8 r;
    r[0] = (bh)f0.x; r[1] = (bh)f0.y; r[2] = (bh)f0.z; r[3] = (bh)f0.w;
    r[4] = (bh)f1.x; r[5] = (bh)f1.y; r[6] = (bh)f1.z; r[7] = (bh)f1.w;
    return r;
}

// ordered-uint pack: 24-bit value | 8-bit inverted local col idx (tie -> smaller idx wins)
__device__ __forceinline__ u32 pack_vi(float v, int inv_idx) {
    u32 u = __float_as_uint(v);
    u32 s = u ^ ((u32)((int)u >> 31) | 0x80000000u);
    return (s & 0xFFFFFF00u) | (u32)inv_idx;
}
__device__ __forceinline__ float unpack_v(u32 p) {
    u32 s = p & 0xFFFFFF00u;
    u32 u = (s & 0x80000000u) ? (s ^ 0x80000000u) : ~s;
    return __uint_as_float(u);
}

// direct global->LDS 16B per lane; lds base must be wave-uniform (dest = base + lane*16)
__device__ __forceinline__ void gl_lds16(const u16* g, u16* l) {
    __builtin_amdgcn_global_load_lds(
        (const __attribute__((address_space(1))) void*)g,
        (__attribute__((address_space(3))) void*)l, 16, 0, 0);
}

// ---------------------------------------------------------------------------
// all 6 weight transposes (fp32 [R,C] -> bf16 [C,R]) in one dispatch
__global__ void transpose_all(const float* s0, u16* d0, const float* s1, u16* d1,
                              const float* s2, u16* d2, const float* s3, u16* d3,
                              const float* s4, u16* d4, const float* s5, u16* d5) {
    __shared__ float t[32][33];
    int b = blockIdx.x;
    const float* src; u16* dst; int R, C, tt;
    if      (b < 512)  { src = s0; dst = d0; R = 1024; C = 512; tt = b; }
    else if (b < 768)  { src = s1; dst = d1; R = 512;  C = 512; tt = b - 512; }
    else if (b < 1024) { src = s2; dst = d2; R = 512;  C = 512; tt = b - 768; }
    else if (b < 1280) { src = s3; dst = d3; R = 512;  C = 512; tt = b - 1024; }
    else if (b < 1536) { src = s4; dst = d4; R = 512;  C = 512; tt = b - 1280; }
    else               { src = s5; dst = d5; R = 512;  C = 256; tt = b - 1536; }
    int ntx = C >> 5;
    int bx = (tt % ntx) * 32, by = (tt / ntx) * 32;
    int x = threadIdx.x, y = threadIdx.y;
    for (int i = 0; i < 32; i += 8)
        t[y + i][x] = src[(size_t)(by + y + i) * C + bx + x];
    __syncthreads();
    for (int i = 0; i < 32; i += 8)
        dst[(size_t)(bx + y + i) * R + by + x] = f2bf(t[x][y + i]);
}

// x fp32 -> bf16
__global__ void cvt_x(const float* __restrict__ x, u16* __restrict__ xb) {
    size_t i = ((size_t)blockIdx.x * 256 + threadIdx.x) * 8;
    bh8 v = ld8_f32(x + i);
    *(bh8*)(xb + i) = v;
}

// ---------------------------------------------------------------------------
// zero-VALU K-loop: 4x global_load_lds(16B) + 8x ds_read_b128 + 16 MFMA per BK=32
template<int KT>
__device__ __forceinline__ void kloop_gl(const u16* __restrict__ Ag, const u16* __restrict__ Bg,
                                         u16* Alds, u16* Blds, f32x4 (&acc)[4][4]) {
    const int tid = threadIdx.x;
    const int wave = tid >> 6, lane = tid & 63;
    const int lr = lane & 15, quad = lane >> 4;
    const int wm = (wave & 1) * 64, wn = (wave >> 1) * 64;
    const int r = tid >> 2, c8 = (tid & 3) * 8;
    const u16* ga0 = Ag + (size_t)r * KT + c8;
    const u16* ga1 = ga0 + (size_t)64 * KT;
    const u16* gb0 = Bg + (size_t)r * KT + c8;
    const u16* gb1 = gb0 + (size_t)64 * KT;
    u16* la = Alds + wave * 512;   // wave-uniform, +1024B per wave
    u16* lb = Blds + wave * 512;
    #pragma unroll
    for (int k0 = 0; k0 < KT; k0 += 32) {
        __syncthreads();                 // prior reads done before LDS overwrite
        gl_lds16(ga0 + k0, la);
        gl_lds16(ga1 + k0, la + 2048);   // rows 64..127 (+4096B)
        gl_lds16(gb0 + k0, lb);
        gl_lds16(gb1 + k0, lb + 2048);
        __syncthreads();                 // drains vmcnt -> LDS writes visible
        bh8 af[4], bf_[4];
        #pragma unroll
        for (int i = 0; i < 4; i++) {
            af[i]  = *(const bh8*)&Alds[(wm + i * 16 + lr) * 32 + quad * 8];
            bf_[i] = *(const bh8*)&Blds[(wn + i * 16 + lr) * 32 + quad * 8];
        }
        #pragma unroll
        for (int mi = 0; mi < 4; mi++)
            #pragma unroll
            for (int ni = 0; ni < 4; ni++)
                acc[mi][ni] = __builtin_amdgcn_mfma_f32_16x16x32_bf16(
                    af[mi], bf_[ni], acc[mi][ni], 0, 0, 0);
    }
}

template<int ACT, int F32OUT>
__device__ __forceinline__ void epilogue(f32x4 (&acc)[4][4], const float* bias,
                                         float* Cf, u16* Cb, int N, int m0, int n0) {
    const int tid = threadIdx.x;
    const int wave = tid >> 6, lane = tid & 63;
    const int lr = lane & 15, quad = lane >> 4;
    const int wm = (wave & 1) * 64, wn = (wave >> 1) * 64;
    #pragma unroll
    for (int ni = 0; ni < 4; ni++) {
        int col = n0 + wn + ni * 16 + lr;
        float bs = bias[col];
        #pragma unroll
        for (int mi = 0; mi < 4; mi++) {
            #pragma unroll
            for (int i = 0; i < 4; i++) {
                int row = m0 + wm + mi * 16 + quad * 4 + i;
                float v = acc[mi][ni][i] + bs;
                if (ACT == 1) v = fmaxf(v, 0.0f);
                if (ACT == 2) v = (v > 0.0f) ? v : 0.01f * v;
                size_t o = (size_t)row * N + col;
                if (F32OUT) Cf[o] = v;
                else        Cb[o] = f2bf(v);
            }
        }
    }
}

// plain GEMM: out = act(A @ B^T + bias)
template<int ACT, int F32OUT, int KT>
__global__ __launch_bounds__(256) void gemm_gl(
    const u16* __restrict__ A, const u16* __restrict__ B, const float* __restrict__ bias,
    float* __restrict__ Cf, u16* __restrict__ Cb, int N)
{
    __shared__ __align__(16) u16 Alds[128 * 32];
    __shared__ __align__(16) u16 Blds[128 * 32];
    const int m0 = blockIdx.y * 128, n0 = blockIdx.x * 128;
    f32x4 acc[4][4] = {};
    kloop_gl<KT>(A + (size_t)m0 * KT, B + (size_t)n0 * KT, Alds, Blds, acc);
    epilogue<ACT, F32OUT>(acc, bias, Cf, Cb, N, m0, n0);
}

// fused e_h / e_t: blockIdx.x<4 -> (whT, wh_b, ehbf), else (wtT, wt_b, etbf)
__global__ __launch_bounds__(256) void ehet_gl(
    const u16* __restrict__ A, const u16* __restrict__ Bh, const u16* __restrict__ Bt,
    const float* __restrict__ bh_, const float* __restrict__ bt_,
    u16* __restrict__ Oh, u16* __restrict__ Ot)
{
    __shared__ __align__(16) u16 Alds[128 * 32];
    __shared__ __align__(16) u16 Blds[128 * 32];
    const int bx = blockIdx.x;
    const int m0 = blockIdx.y * 128, n0 = (bx & 3) * 128;
    const u16* B = (bx < 4) ? Bh : Bt;
    const float* bias = (bx < 4) ? bh_ : bt_;
    u16* O = (bx < 4) ? Oh : Ot;
    f32x4 acc[4][4] = {};
    kloop_gl<512>(A + (size_t)m0 * 512, B + (size_t)n0 * 512, Alds, Blds, acc);
    epilogue<0, 0>(acc, bias, nullptr, O, 512, m0, n0);
}

// fused emb = lrelu(s1@l1+b1) + lrelu(s2@l2+b2)
__global__ __launch_bounds__(256) void lin12_gl(
    const u16* __restrict__ A1, const u16* __restrict__ B1, const float* __restrict__ b1,
    const u16* __restrict__ A2, const u16* __restrict__ B2, const float* __restrict__ b2,
    u16* __restrict__ O)
{
    __shared__ __align__(16) u16 Alds[128 * 32];
    __shared__ __align__(16) u16 Blds[128 * 32];
    const int m0 = blockIdx.y * 128, n0 = blockIdx.x * 128;
    f32x4 acc1[4][4] = {}, acc2[4][4] = {};
    kloop_gl<512>(A1 + (size_t)m0 * 512, B1 + (size_t)n0 * 512, Alds, Blds, acc1);
    kloop_gl<512>(A2 + (size_t)m0 * 512, B2 + (size_t)n0 * 512, Alds, Blds, acc2);
    const int tid = threadIdx.x;
    const int wave = tid >> 6, lane = tid & 63;
    const int lr = lane & 15, quad = lane >> 4;
    const int wm = (wave & 1) * 64, wn = (wave >> 1) * 64;
    #pragma unroll
    for (int ni = 0; ni < 4; ni++) {
        int col = n0 + wn + ni * 16 + lr;
        float bs1 = b1[col], bs2 = b2[col];
        #pragma unroll
        for (int mi = 0; mi < 4; mi++) {
            #pragma unroll
            for (int i = 0; i < 4; i++) {
                int row = m0 + wm + mi * 16 + quad * 4 + i;
                float v1 = acc1[mi][ni][i] + bs1;
                v1 = (v1 > 0.0f) ? v1 : 0.01f * v1;
                float v2 = acc2[mi][ni][i] + bs2;
                v2 = (v2 > 0.0f) ? v2 : 0.01f * v2;
                O[(size_t)row * 512 + col] = f2bf(v1 + v2);
            }
        }
    }
}

// ---------------------------------------------------------------------------
// fused logits GEMM + branchless packed top-6 over a 256-col span.
// Grid (32,64). Packed key = 24-bit ordered value | 8-bit inverted local idx.
__global__ __launch_bounds__(256) void logits_topk(
    const u16* __restrict__ Ah, const u16* __restrict__ Bt, u32* __restrict__ tvp)
{
    __shared__ __align__(16) u16 Alds[128 * 32];
    __shared__ __align__(16) u16 Blds[128 * 32];
    __shared__ u32 S[128 * 65];
    const int tid = threadIdx.x;
    const int m0 = blockIdx.y * 128;
    const int cb0 = blockIdx.x * 256;
    const int lane = tid & 63, wave = tid >> 6;
    const int wm = (wave & 1) * 64, wn = (wave >> 1) * 64;
    const int lr = lane & 15, quad = lane >> 4;
    const int srow = tid >> 1, scg = tid & 1;

    u32 v0 = 0, v1 = 0, v2 = 0, v3 = 0, v4 = 0, v5 = 0;

    for (int nt = 0; nt < 2; nt++) {
        f32x4 acc[4][4] = {};
        kloop_gl<512>(Ah + (size_t)m0 * 512,
                      Bt + (size_t)(cb0 + nt * 128) * 512, Alds, Blds, acc);
        #pragma unroll
        for (int half = 0; half < 2; half++) {
            __syncthreads();
            if ((wave >> 1) == half) {
                #pragma unroll
                for (int mi = 0; mi < 4; mi++)
                    #pragma unroll
                    for (int ni = 0; ni < 4; ni++)
                        #pragma unroll
                        for (int i = 0; i < 4; i++) {
                            int colLocal = nt * 128 + half * 64 + ni * 16 + lr;
                            S[(wm + mi * 16 + quad * 4 + i) * 65 + ni * 16 + lr]
                                = pack_vi(acc[mi][ni][i], 255 - colLocal);
                        }
            }
            __syncthreads();
            const u32* Sr = &S[srow * 65 + scg * 32];
            #pragma unroll 8
            for (int c = 0; c < 32; c++) {
                u32 x = Sr[c];
                v5 = max(v5, min(v4, x));
                v4 = max(v4, min(v3, x));
                v3 = max(v3, min(v2, x));
                v2 = max(v2, min(v1, x));
                v1 = max(v1, min(v0, x));
                v0 = max(v0, x);
            }
        }
    }
    // merge the two column-group lists per row through LDS
    __syncthreads();
    {
        u32* dst = &S[srow * 65 + scg * 6];
        dst[0] = v0; dst[1] = v1; dst[2] = v2; dst[3] = v3; dst[4] = v4; dst[5] = v5;
    }
    __syncthreads();
    if (tid < 128) {
        u32 m0v = 0, m1v = 0, m2v = 0, m3v = 0, m4v = 0, m5v = 0;
        const u32* Sr = &S[tid * 65];
        #pragma unroll
        for (int s = 0; s < 12; s++) {
            u32 x = Sr[s];
            m5v = max(m5v, min(m4v, x));
            m4v = max(m4v, min(m3v, x));
            m3v = max(m3v, min(m2v, x));
            m2v = max(m2v, min(m1v, x));
            m1v = max(m1v, min(m0v, x));
            m0v = max(m0v, x);
        }
        u32* dst = tvp + (size_t)(m0 + tid) * 192 + blockIdx.x * 6;
        dst[0] = m0v; dst[1] = m1v; dst[2] = m2v;
        dst[3] = m3v; dst[4] = m4v; dst[5] = m5v;
    }
}

// merge 32 packed partial top-6 lists per row -> final top-6 (fp32 val + idx)
__global__ void topk_merge(const u32* __restrict__ tvp,
                           float* __restrict__ tv, int* __restrict__ ti)
{
    int r = blockIdx.x * 256 + threadIdx.x;
    u32 v[6]; int ix[6];
    #pragma unroll
    for (int j = 0; j < 6; j++) { v[j] = 0; ix[j] = 0; }
    const u32* pv = tvp + (size_t)r * 192;
    for (int b = 0; b < 32; b++) {
        #pragma unroll
        for (int j2 = 0; j2 < 6; j2++) {
            u32 p = pv[b * 6 + j2];
            if (p > v[5]) {
                v[5] = p; ix[5] = b * 256 + 255 - (int)(p & 255u);
                #pragma unroll
                for (int j = 5; j > 0; j--) {
                    if (v[j] > v[j - 1]) {
                        u32 tf = v[j]; v[j] = v[j - 1]; v[j - 1] = tf;
                        int tx = ix[j]; ix[j] = ix[j - 1]; ix[j - 1] = tx;
                    }
                }
            }
        }
    }
    #pragma unroll
    for (int j = 0; j < 6; j++) {
        tv[(size_t)r * 6 + j] = unpack_v(v[j]) * SCALE_F;
        ti[(size_t)r * 6 + j] = ix[j];
    }
}

// ---------------------------------------------------------------------------
__global__ __launch_bounds__(256) void neighbor_kernel(
    const u16* __restrict__ eH, const u16* __restrict__ eT,
    const float* __restrict__ tv, const int* __restrict__ ti,
    u16* __restrict__ s1, u16* __restrict__ s2)
{
    __shared__ float part[24];
    const int n = blockIdx.x, tid = threadIdx.x;
    const int lane = tid & 63, wave = tid >> 6;
    float tw[6]; int id[6];
    #pragma unroll
    for (int j = 0; j < 6; j++) {
        tw[j] = tv[n * 6 + j];
        int t = ti[n * 6 + j];
        id[j] = ((unsigned)t < 8192u) ? t : 0;
    }
    float mx = tw[0];
    #pragma unroll
    for (int j = 1; j < 6; j++) mx = fmaxf(mx, tw[j]);
    float p[6]; float ps = 0.f;
    #pragma unroll
    for (int j = 0; j < 6; j++) { p[j] = __expf(tw[j] - mx); ps += p[j]; }
    float inv = 1.0f / ps;
    #pragma unroll
    for (int j = 0; j < 6; j++) p[j] *= inv;

    const size_t base = (size_t)n * 512;
    float eh0 = bf2f(eH[base + tid]), eh1 = bf2f(eH[base + tid + 256]);
    float nb0[6], nb1[6];
    #pragma unroll
    for (int j = 0; j < 6; j++) {
        size_t b = (size_t)id[j] * 512;
        nb0[j] = bf2f(eT[b + tid]); nb1[j] = bf2f(eT[b + tid + 256]);
    }
    #pragma unroll
    for (int j = 0; j < 6; j++) {
        float e0 = p[j] * nb0[j] + (1.f - p[j]) * eh0;
        float e1 = p[j] * nb1[j] + (1.f - p[j]) * eh1;
        float g0 = tanhf(eh0 + e0), g1 = tanhf(eh1 + e1);
        float s = nb0[j] * g0 + nb1[j] * g1;
        #pragma unroll
        for (int off = 32; off > 0; off >>= 1) s += __shfl_down(s, off);
        if (lane == 0) part[wave * 6 + j] = s;
    }
    __syncthreads();
    float ka[6];
    #pragma unroll
    for (int j = 0; j < 6; j++)
        ka[j] = part[j] + part[6 + j] + part[12 + j] + part[18 + j];
    float m2 = ka[0];
    #pragma unroll
    for (int j = 1; j < 6; j++) m2 = fmaxf(m2, ka[j]);
    float kp[6]; float ks = 0.f;
    #pragma unroll
    for (int j = 0; j < 6; j++) { kp[j] = __expf(ka[j] - m2); ks += kp[j]; }
    float inv2 = 1.0f / ks;
    #pragma unroll
    for (int j = 0; j < 6; j++) kp[j] *= inv2;
    float eN0 = 0.f, eN1 = 0.f;
    #pragma unroll
    for (int j = 0; j < 6; j++) { eN0 += kp[j] * nb0[j]; eN1 += kp[j] * nb1[j]; }
    s1[base + tid]       = f2bf(eh0 + eN0);
    s1[base + tid + 256] = f2bf(eh1 + eN1);
    s2[base + tid]       = f2bf(eh0 * eN0);
    s2[base + tid + 256] = f2bf(eh1 * eN1);
}

// ---------------------------------------------------------------------------
__global__ void colsum_kernel(const u16* __restrict__ h, float* __restrict__ colsum) {
    int tid = threadIdx.x;
    int n0 = blockIdx.x * 32;
    float a0 = 0.f, a1 = 0.f;
    for (int k = 0; k < 32; k++) {
        size_t b = (size_t)(n0 + k) * 512;
        a0 += bf2f(h[b + tid]); a1 += bf2f(h[b + tid + 256]);
    }
    atomicAdd(&colsum[tid], a0);
    atomicAdd(&colsum[tid + 256], a1);
}

__global__ void meanmix_kernel(u16* __restrict__ h, const float* __restrict__ colsum) {
    size_t i = ((size_t)blockIdx.x * 256 + threadIdx.x) * 8;
    int col = (int)(i & 511);
    union { int4 v; u16 s[8]; } u;
    u.v = *(const int4*)&h[i];
    #pragma unroll
    for (int j = 0; j < 8; j++)
        u.s[j] = f2bf((bf2f(u.s[j]) + colsum[col + j] * (1.0f / 8192.0f)) * 0.5f);
    *(int4*)&h[i] = u.v;
}

__global__ __launch_bounds__(256) void att2_kernel(
    const float* __restrict__ a1, const float* __restrict__ w,
    const float* __restrict__ b, float* __restrict__ att)
{
    int row = blockIdx.x * 4 + (threadIdx.x >> 6);
    int lane = threadIdx.x & 63;
    const float* pr = a1 + (size_t)row * 256;
    float s = 0.f;
    #pragma unroll
    for (int k = 0; k < 4; k++) { int c = lane + k * 64; s += pr[c] * w[c]; }
    #pragma unroll
    for (int off = 32; off > 0; off >>= 1) s += __shfl_down(s, off);
    if (lane == 0) att[row] = s + b[0];
}

__global__ void att_prep(const float* __restrict__ att, float* __restrict__ scal) {
    __shared__ float red[256];
    int tid = threadIdx.x;
    float mx = -INFINITY;
    for (int i = tid; i < 8192; i += 256) mx = fmaxf(mx, att[i]);
    red[tid] = mx; __syncthreads();
    for (int s = 128; s > 0; s >>= 1) {
        if (tid < s) red[tid] = fmaxf(red[tid], red[tid + s]);
        __syncthreads();
    }
    mx = red[0]; __syncthreads();
    float sm = 0.f;
    for (int i = tid; i < 8192; i += 256) sm += __expf(att[i] - mx);
    red[tid] = sm; __syncthreads();
    for (int s = 128; s > 0; s >>= 1) {
        if (tid < s) red[tid] += red[tid + s];
        __syncthreads();
    }
    if (tid == 0) { scal[0] = mx; scal[1] = red[0]; }
}

__global__ void pooled_kernel(const u16* __restrict__ emb, const float* __restrict__ att,
                              const float* __restrict__ scal, float* __restrict__ pooled) {
    int tid = threadIdx.x;
    int n0 = blockIdx.x * 32;
    float mx = scal[0]; float inv = 1.0f / scal[1];
    float a0 = 0.f, a1 = 0.f;
    for (int k = 0; k < 32; k++) {
        int n = n0 + k;
        float w = __expf(att[n] - mx) * inv;
        size_t b = (size_t)n * 512;
        a0 += w * bf2f(emb[b + tid]);
        a1 += w * bf2f(emb[b + tid + 256]);
    }
    atomicAdd(&pooled[tid], a0);
    atomicAdd(&pooled[tid + 256], a1);
}

__global__ void final_kernel(const float* __restrict__ pooled,
                             const float* __restrict__ g, const float* __restrict__ bln,
                             const float* __restrict__ fcw, const float* __restrict__ fcb,
                             float* __restrict__ out) {
    __shared__ float red[256];
    int tid = threadIdx.x;
    float x0 = pooled[tid], x1 = pooled[tid + 256];
    red[tid] = x0 + x1; __syncthreads();
    for (int s = 128; s > 0; s >>= 1) { if (tid < s) red[tid] += red[tid + s]; __syncthreads(); }
    float mu = red[0] * (1.0f / 512.0f); __syncthreads();
    float d0 = x0 - mu, d1 = x1 - mu;
    red[tid] = d0 * d0 + d1 * d1; __syncthreads();
    for (int s = 128; s > 0; s >>= 1) { if (tid < s) red[tid] += red[tid + s]; __syncthreads(); }
    float var = red[0] * (1.0f / 512.0f); __syncthreads();
    float rstd = rsqrtf(var + 1e-5f);
    float l0 = d0 * rstd * g[tid]       + bln[tid];
    float l1 = d1 * rstd * g[tid + 256] + bln[tid + 256];
    red[tid] = l0 * fcw[tid * 2] + l1 * fcw[(tid + 256) * 2]; __syncthreads();
    for (int s = 128; s > 0; s >>= 1) { if (tid < s) red[tid] += red[tid + s]; __syncthreads(); }
    float o0 = red[0] + fcb[0]; __syncthreads();
    red[tid] = l0 * fcw[tid * 2 + 1] + l1 * fcw[(tid + 256) * 2 + 1]; __syncthreads();
    for (int s = 128; s > 0; s >>= 1) { if (tid < s) red[tid] += red[tid + s]; __syncthreads(); }
    float o1 = red[0] + fcb[1];
    if (tid == 0) {
        float m = fmaxf(o0, o1);
        float e0 = expf(o0 - m), e1 = expf(o1 - m);
        float se = e0 + e1;
        out[0] = o0;
        out[1] = o1;
        out[2] = e0 / se;
        out[3] = e1 / se;
        out[4] = (o0 >= o1) ? 0.0f : 1.0f;
    }
}

// ---------------------------------------------------------------------------
extern "C" void kernel_launch(void* const* d_in, const int* in_sizes, int n_in,
                              void* d_out, int out_size, void* d_ws, size_t ws_size,
                              hipStream_t stream)
{
    const float* x      = (const float*)d_in[0];
    const float* fc1_w  = (const float*)d_in[1];
    const float* fc1_b  = (const float*)d_in[2];
    const float* wh_w   = (const float*)d_in[3];
    const float* wh_b   = (const float*)d_in[4];
    const float* wt_w   = (const float*)d_in[5];
    const float* wt_b   = (const float*)d_in[6];
    const float* lin1_w = (const float*)d_in[7];
    const float* lin1_b = (const float*)d_in[8];
    const float* lin2_w = (const float*)d_in[9];
    const float* lin2_b = (const float*)d_in[10];
    const float* att1_w = (const float*)d_in[11];
    const float* att1_b = (const float*)d_in[12];
    const float* att2_w = (const float*)d_in[13];
    const float* att2_b = (const float*)d_in[14];
    const float* ln_g   = (const float*)d_in[15];
    const float* ln_b   = (const float*)d_in[16];
    const float* fc_w   = (const float*)d_in[17];
    const float* fc_b   = (const float*)d_in[18];
    float* out = (float*)d_out;
    char* ws = (char*)d_ws;

    // Workspace layout (ends 48,234,496 — verified fits in R3-R5)
    u16*   fc1T   = (u16*)(ws + 0);
    u16*   whT    = (u16*)(ws + 1048576);
    u16*   wtT    = (u16*)(ws + 1572864);
    u16*   l1T    = (u16*)(ws + 2097152);
    u16*   l2T    = (u16*)(ws + 2621440);
    u16*   a1T    = (u16*)(ws + 3145728);
    float* tv     = (float*)(ws + 3407872);
    int*   ti     = (int*)(ws + 3604480);
    float* att    = (float*)(ws + 3801088);
    float* colsum = (float*)(ws + 3833856);
    float* pooled = (float*)(ws + 3835904);
    float* scal   = (float*)(ws + 3837952);
    u32*   tvp    = (u32*)(ws + 4194304);    // 8192*192*4 = 6,291,456 (packed)
    u16*   hbf    = (u16*)(ws + 14680064);   // 8 MB  [h; later s1]
    u16*   ehbf   = (u16*)(ws + 23068672);   // 8 MB  [e_h; later a1 fp32]
    u16*   etbf   = (u16*)(ws + 31457280);   // 8 MB  [e_t; later emb]
    u16*   s2bf   = (u16*)(ws + 39845888);   // 8 MB  [s2]
    u16*   xbf    = (u16*)(ws + 23068672);   // 16 MB (x bf16; dead after fc1)
    float* a1f    = (float*)(ws + 23068672); // 8 MB fp32 (after e_h dead)

    transpose_all<<<1664, dim3(32, 8), 0, stream>>>(fc1_w, fc1T, wh_w, whT, wt_w, wtT,
                                                    lin1_w, l1T, lin2_w, l2T, att1_w, a1T);
    cvt_x<<<4096, 256, 0, stream>>>(x, xbf);
    hipMemsetAsync(colsum, 0, 2048, stream);

    // h = relu(x @ fc1 + b) -> bf16
    gemm_gl<1, 0, 1024><<<dim3(4, 64), 256, 0, stream>>>(xbf, fc1T, fc1_b, nullptr, hbf, 512);
    colsum_kernel<<<256, 256, 0, stream>>>(hbf, colsum);
    meanmix_kernel<<<2048, 256, 0, stream>>>(hbf, colsum);

    // e_h, e_t fused
    ehet_gl<<<dim3(8, 64), 256, 0, stream>>>(hbf, whT, wtT, wh_b, wt_b, ehbf, etbf);

    // fused logits + packed top-6
    logits_topk<<<dim3(32, 64), 256, 0, stream>>>(ehbf, etbf, tvp);
    topk_merge<<<32, 256, 0, stream>>>(tvp, tv, ti);

    // neighbor aggregation -> s1 (hbf), s2 (s2bf)
    neighbor_kernel<<<8192, 256, 0, stream>>>(ehbf, etbf, tv, ti, hbf, s2bf);

    // emb = lrelu(s1@lin1+b) + lrelu(s2@lin2+b) -> etbf
    lin12_gl<<<dim3(4, 64), 256, 0, stream>>>(hbf, l1T, lin1_b, s2bf, l2T, lin2_b, etbf);

    // att path
    gemm_gl<2, 1, 512><<<dim3(2, 64), 256, 0, stream>>>(etbf, a1T, att1_b, a1f, nullptr, 256);
    att2_kernel<<<2048, 256, 0, stream>>>(a1f, att2_w, att2_b, att);
    att_prep<<<1, 256, 0, stream>>>(att, scal);
    hipMemsetAsync(pooled, 0, 2048, stream);
    pooled_kernel<<<256, 256, 0, stream>>>(etbf, att, scal, pooled);

    final_kernel<<<1, 256, 0, stream>>>(pooled, ln_g, ln_b, fc_w, fc_b, out);
}

// Round 7
// 438.135 us; speedup vs baseline: 1.7947x; 1.0809x over previous
//
#include <hip/hip_runtime.h>
#include <hip/hip_bf16.h>
#include <cstdint>
#include <math.h>

typedef unsigned short u16;
typedef unsigned int u32;
typedef __bf16 bh;
typedef bh bh8 __attribute__((ext_vector_type(8)));
typedef float f32x4 __attribute__((ext_vector_type(4)));

#define SCALE_F 0.04419417382415922f  // 512^-0.5

__device__ __forceinline__ float bf2f(u16 u) {
    union { float f; unsigned int i; } v; v.i = ((unsigned int)u) << 16; return v.f;
}
__device__ __forceinline__ u16 f2bf(float f) {
    __hip_bfloat16 h = __float2bfloat16(f);
    return __builtin_bit_cast(u16, h);
}
__device__ __forceinline__ bh8 ld8_f32(const float* p) {
    float4 f0 = *(const float4*)p;
    float4 f1 = *(const float4*)(p + 4);
    bh8 r;
    r[0] = (bh)f0.x; r[1] = (bh)f0.y; r[2] = (bh)f0.z; r[3] = (bh)f0.w;
    r[4] = (bh)f1.x; r[5] = (bh)f1.y; r[6] = (bh)f1.z; r[7] = (bh)f1.w;
    return r;
}

// ordered-uint transforms (monotone with float order)
__device__ __forceinline__ u32 ordf(float f) {
    u32 u = __float_as_uint(f);
    return u ^ ((u32)((int)u >> 31) | 0x80000000u);
}
__device__ __forceinline__ float unordf(u32 s) {
    u32 u = (s & 0x80000000u) ? (s ^ 0x80000000u) : ~s;
    return __uint_as_float(u);
}
// 24-bit ordered value | 8-bit inverted local col idx (tie -> smaller idx wins)
__device__ __forceinline__ u32 pack_vi(float v, int inv_idx) {
    return (ordf(v) & 0xFFFFFF00u) | (u32)inv_idx;
}
__device__ __forceinline__ float unpack_v(u32 p) {
    return unordf(p & 0xFFFFFF00u);
}

// direct global->LDS 16B per lane; lds base wave-uniform (dest = base + lane*16)
__device__ __forceinline__ void gl_lds16(const u16* g, u16* l) {
    __builtin_amdgcn_global_load_lds(
        (const __attribute__((address_space(1))) void*)g,
        (__attribute__((address_space(3))) void*)l, 16, 0, 0);
}

// ---------------------------------------------------------------------------
// 6 weight transposes (fp32 [R,C] -> bf16 [C,R]) + x fp32->bf16, one dispatch
__global__ void transpose_cvt(const float* s0, u16* d0, const float* s1, u16* d1,
                              const float* s2, u16* d2, const float* s3, u16* d3,
                              const float* s4, u16* d4, const float* s5, u16* d5,
                              const float* xs, u16* xd) {
    int b = blockIdx.x;
    if (b >= 1664) {  // cvt_x part: 4096 blocks, 8 elems/thread
        int t = threadIdx.y * 32 + threadIdx.x;
        size_t i = ((size_t)(b - 1664) * 256 + t) * 8;
        *(bh8*)(xd + i) = ld8_f32(xs + i);
        return;
    }
    __shared__ float tsh[32][33];
    const float* src; u16* dst; int R, C, tt;
    if      (b < 512)  { src = s0; dst = d0; R = 1024; C = 512; tt = b; }
    else if (b < 768)  { src = s1; dst = d1; R = 512;  C = 512; tt = b - 512; }
    else if (b < 1024) { src = s2; dst = d2; R = 512;  C = 512; tt = b - 768; }
    else if (b < 1280) { src = s3; dst = d3; R = 512;  C = 512; tt = b - 1024; }
    else if (b < 1536) { src = s4; dst = d4; R = 512;  C = 512; tt = b - 1280; }
    else               { src = s5; dst = d5; R = 512;  C = 256; tt = b - 1536; }
    int ntx = C >> 5;
    int bx = (tt % ntx) * 32, by = (tt / ntx) * 32;
    int x = threadIdx.x, y = threadIdx.y;
    for (int i = 0; i < 32; i += 8)
        tsh[y + i][x] = src[(size_t)(by + y + i) * C + bx + x];
    __syncthreads();
    for (int i = 0; i < 32; i += 8)
        dst[(size_t)(bx + y + i) * R + by + x] = f2bf(tsh[x][y + i]);
}

// ---------------------------------------------------------------------------
// double-buffered direct-to-LDS K-loop: one barrier/iter; next iter's loads
// (into the other buffer) are in flight across the current iter's compute,
// so the barrier's vmcnt(0) drain overlaps ~a full iteration of MFMA+ds_read.
// Alds/Blds must be sized 2*128*32 u16 (16KB each).
template<int KT>
__device__ __forceinline__ void kloop_db(const u16* __restrict__ Ag, const u16* __restrict__ Bg,
                                         u16* Alds, u16* Blds, f32x4 (&acc)[4][4]) {
    const int tid = threadIdx.x;
    const int wave = tid >> 6, lane = tid & 63;
    const int lr = lane & 15, quad = lane >> 4;
    const int wm = (wave & 1) * 64, wn = (wave >> 1) * 64;
    const int r = tid >> 2, c8 = (tid & 3) * 8;
    const u16* ga0 = Ag + (size_t)r * KT + c8;
    const u16* ga1 = ga0 + (size_t)64 * KT;
    const u16* gb0 = Bg + (size_t)r * KT + c8;
    const u16* gb1 = gb0 + (size_t)64 * KT;
    {   // prologue -> buf0
        u16* la = Alds + wave * 512;
        u16* lb = Blds + wave * 512;
        gl_lds16(ga0, la);  gl_lds16(ga1, la + 2048);
        gl_lds16(gb0, lb);  gl_lds16(gb1, lb + 2048);
    }
    #pragma unroll
    for (int k0 = 0; k0 < KT; k0 += 32) {
        const int cur = (k0 >> 5) & 1;
        __syncthreads();   // drains loads into cur; prior-iter LDS reads are consumed
        if (k0 + 32 < KT) {
            u16* la = Alds + (1 - cur) * 4096 + wave * 512;
            u16* lb = Blds + (1 - cur) * 4096 + wave * 512;
            gl_lds16(ga0 + k0 + 32, la);  gl_lds16(ga1 + k0 + 32, la + 2048);
            gl_lds16(gb0 + k0 + 32, lb);  gl_lds16(gb1 + k0 + 32, lb + 2048);
        }
        const u16* Ab = Alds + cur * 4096;
        const u16* Bb = Blds + cur * 4096;
        bh8 af[4], bf_[4];
        #pragma unroll
        for (int i = 0; i < 4; i++) {
            af[i]  = *(const bh8*)&Ab[(wm + i * 16 + lr) * 32 + quad * 8];
            bf_[i] = *(const bh8*)&Bb[(wn + i * 16 + lr) * 32 + quad * 8];
        }
        #pragma unroll
        for (int mi = 0; mi < 4; mi++)
            #pragma unroll
            for (int ni = 0; ni < 4; ni++)
                acc[mi][ni] = __builtin_amdgcn_mfma_f32_16x16x32_bf16(
                    af[mi], bf_[ni], acc[mi][ni], 0, 0, 0);
    }
}

template<int ACT, int F32OUT>
__device__ __forceinline__ void epilogue(f32x4 (&acc)[4][4], const float* bias,
                                         float* Cf, u16* Cb, int N, int m0, int n0) {
    const int tid = threadIdx.x;
    const int wave = tid >> 6, lane = tid & 63;
    const int lr = lane & 15, quad = lane >> 4;
    const int wm = (wave & 1) * 64, wn = (wave >> 1) * 64;
    #pragma unroll
    for (int ni = 0; ni < 4; ni++) {
        int col = n0 + wn + ni * 16 + lr;
        float bs = bias[col];
        #pragma unroll
        for (int mi = 0; mi < 4; mi++) {
            #pragma unroll
            for (int i = 0; i < 4; i++) {
                int row = m0 + wm + mi * 16 + quad * 4 + i;
                float v = acc[mi][ni][i] + bs;
                if (ACT == 1) v = fmaxf(v, 0.0f);
                if (ACT == 2) v = (v > 0.0f) ? v : 0.01f * v;
                size_t o = (size_t)row * N + col;
                if (F32OUT) Cf[o] = v;
                else        Cb[o] = f2bf(v);
            }
        }
    }
}

template<int ACT, int F32OUT, int KT>
__global__ __launch_bounds__(256) void gemm_gl(
    const u16* __restrict__ A, const u16* __restrict__ B, const float* __restrict__ bias,
    float* __restrict__ Cf, u16* __restrict__ Cb, int N)
{
    __shared__ __align__(16) u16 Alds[2 * 128 * 32];
    __shared__ __align__(16) u16 Blds[2 * 128 * 32];
    const int m0 = blockIdx.y * 128, n0 = blockIdx.x * 128;
    f32x4 acc[4][4] = {};
    kloop_db<KT>(A + (size_t)m0 * KT, B + (size_t)n0 * KT, Alds, Blds, acc);
    epilogue<ACT, F32OUT>(acc, bias, Cf, Cb, N, m0, n0);
}

// fused e_h / e_t
__global__ __launch_bounds__(256) void ehet_gl(
    const u16* __restrict__ A, const u16* __restrict__ Bh, const u16* __restrict__ Bt,
    const float* __restrict__ bh_, const float* __restrict__ bt_,
    u16* __restrict__ Oh, u16* __restrict__ Ot)
{
    __shared__ __align__(16) u16 Alds[2 * 128 * 32];
    __shared__ __align__(16) u16 Blds[2 * 128 * 32];
    const int bx = blockIdx.x;
    const int m0 = blockIdx.y * 128, n0 = (bx & 3) * 128;
    const u16* B = (bx < 4) ? Bh : Bt;
    const float* bias = (bx < 4) ? bh_ : bt_;
    u16* O = (bx < 4) ? Oh : Ot;
    f32x4 acc[4][4] = {};
    kloop_db<512>(A + (size_t)m0 * 512, B + (size_t)n0 * 512, Alds, Blds, acc);
    epilogue<0, 0>(acc, bias, nullptr, O, 512, m0, n0);
}

// fused emb = lrelu(s1@l1+b1) + lrelu(s2@l2+b2)
__global__ __launch_bounds__(256) void lin12_gl(
    const u16* __restrict__ A1, const u16* __restrict__ B1, const float* __restrict__ b1,
    const u16* __restrict__ A2, const u16* __restrict__ B2, const float* __restrict__ b2,
    u16* __restrict__ O)
{
    __shared__ __align__(16) u16 Alds[2 * 128 * 32];
    __shared__ __align__(16) u16 Blds[2 * 128 * 32];
    const int m0 = blockIdx.y * 128, n0 = blockIdx.x * 128;
    f32x4 acc1[4][4] = {}, acc2[4][4] = {};
    kloop_db<512>(A1 + (size_t)m0 * 512, B1 + (size_t)n0 * 512, Alds, Blds, acc1);
    kloop_db<512>(A2 + (size_t)m0 * 512, B2 + (size_t)n0 * 512, Alds, Blds, acc2);
    const int tid = threadIdx.x;
    const int wave = tid >> 6, lane = tid & 63;
    const int lr = lane & 15, quad = lane >> 4;
    const int wm = (wave & 1) * 64, wn = (wave >> 1) * 64;
    #pragma unroll
    for (int ni = 0; ni < 4; ni++) {
        int col = n0 + wn + ni * 16 + lr;
        float bs1 = b1[col], bs2 = b2[col];
        #pragma unroll
        for (int mi = 0; mi < 4; mi++) {
            #pragma unroll
            for (int i = 0; i < 4; i++) {
                int row = m0 + wm + mi * 16 + quad * 4 + i;
                float v1 = acc1[mi][ni][i] + bs1;
                v1 = (v1 > 0.0f) ? v1 : 0.01f * v1;
                float v2 = acc2[mi][ni][i] + bs2;
                v2 = (v2 > 0.0f) ? v2 : 0.01f * v2;
                O[(size_t)row * 512 + col] = f2bf(v1 + v2);
            }
        }
    }
}

// ---------------------------------------------------------------------------
// fused logits GEMM + branchless packed top-6 over a 256-col span. Grid (32,64).
__global__ __launch_bounds__(256) void logits_topk(
    const u16* __restrict__ Ah, const u16* __restrict__ Bt, u32* __restrict__ tvp)
{
    __shared__ __align__(16) u16 Alds[2 * 128 * 32];
    __shared__ __align__(16) u16 Blds[2 * 128 * 32];
    __shared__ u32 S[128 * 65];
    const int tid = threadIdx.x;
    const int m0 = blockIdx.y * 128;
    const int cb0 = blockIdx.x * 256;
    const int lane = tid & 63, wave = tid >> 6;
    const int wm = (wave & 1) * 64, wn = (wave >> 1) * 64;
    const int lr = lane & 15, quad = lane >> 4;
    const int srow = tid >> 1, scg = tid & 1;

    u32 v0 = 0, v1 = 0, v2 = 0, v3 = 0, v4 = 0, v5 = 0;

    for (int nt = 0; nt < 2; nt++) {
        f32x4 acc[4][4] = {};
        kloop_db<512>(Ah + (size_t)m0 * 512,
                      Bt + (size_t)(cb0 + nt * 128) * 512, Alds, Blds, acc);
        #pragma unroll
        for (int half = 0; half < 2; half++) {
            __syncthreads();
            if ((wave >> 1) == half) {
                #pragma unroll
                for (int mi = 0; mi < 4; mi++)
                    #pragma unroll
                    for (int ni = 0; ni < 4; ni++)
                        #pragma unroll
                        for (int i = 0; i < 4; i++) {
                            int colLocal = nt * 128 + half * 64 + ni * 16 + lr;
                            S[(wm + mi * 16 + quad * 4 + i) * 65 + ni * 16 + lr]
                                = pack_vi(acc[mi][ni][i], 255 - colLocal);
                        }
            }
            __syncthreads();
            const u32* Sr = &S[srow * 65 + scg * 32];
            #pragma unroll 8
            for (int c = 0; c < 32; c++) {
                u32 x = Sr[c];
                v5 = max(v5, min(v4, x));
                v4 = max(v4, min(v3, x));
                v3 = max(v3, min(v2, x));
                v2 = max(v2, min(v1, x));
                v1 = max(v1, min(v0, x));
                v0 = max(v0, x);
            }
        }
    }
    __syncthreads();
    {
        u32* dst = &S[srow * 65 + scg * 6];
        dst[0] = v0; dst[1] = v1; dst[2] = v2; dst[3] = v3; dst[4] = v4; dst[5] = v5;
    }
    __syncthreads();
    if (tid < 128) {
        u32 m0v = 0, m1v = 0, m2v = 0, m3v = 0, m4v = 0, m5v = 0;
        const u32* Sr = &S[tid * 65];
        #pragma unroll
        for (int s = 0; s < 12; s++) {
            u32 x = Sr[s];
            m5v = max(m5v, min(m4v, x));
            m4v = max(m4v, min(m3v, x));
            m3v = max(m3v, min(m2v, x));
            m2v = max(m2v, min(m1v, x));
            m1v = max(m1v, min(m0v, x));
            m0v = max(m0v, x);
        }
        u32* dst = tvp + (size_t)(m0 + tid) * 192 + blockIdx.x * 6;
        dst[0] = m0v; dst[1] = m1v; dst[2] = m2v;
        dst[3] = m3v; dst[4] = m4v; dst[5] = m5v;
    }
}

// merge 32 packed partial top-6 lists per row -> final top-6 (fp32 val + idx)
__global__ void topk_merge(const u32* __restrict__ tvp,
                           float* __restrict__ tv, int* __restrict__ ti)
{
    int r = blockIdx.x * 64 + threadIdx.x;
    u32 v[6]; int ix[6];
    #pragma unroll
    for (int j = 0; j < 6; j++) { v[j] = 0; ix[j] = 0; }
    const u32* pv = tvp + (size_t)r * 192;
    for (int b = 0; b < 32; b++) {
        #pragma unroll
        for (int j2 = 0; j2 < 6; j2++) {
            u32 p = pv[b * 6 + j2];
            if (p <= v[5]) break;     // group is descending: rest can't insert
            v[5] = p; ix[5] = b * 256 + 255 - (int)(p & 255u);
            #pragma unroll
            for (int j = 5; j > 0; j--) {
                if (v[j] > v[j - 1]) {
                    u32 tf = v[j]; v[j] = v[j - 1]; v[j - 1] = tf;
                    int tx = ix[j]; ix[j] = ix[j - 1]; ix[j - 1] = tx;
                }
            }
        }
    }
    #pragma unroll
    for (int j = 0; j < 6; j++) {
        tv[(size_t)r * 6 + j] = unpack_v(v[j]) * SCALE_F;
        ti[(size_t)r * 6 + j] = ix[j];
    }
}

// ---------------------------------------------------------------------------
// neighbor aggregation, one WAVE per row (no block barriers). fp32 math.
__global__ __launch_bounds__(256) void neighbor_kernel(
    const u16* __restrict__ eH, const u16* __restrict__ eT,
    const float* __restrict__ tv, const int* __restrict__ ti,
    u16* __restrict__ s1, u16* __restrict__ s2)
{
    const int tid = threadIdx.x, wave = tid >> 6, lane = tid & 63;
    const int n = blockIdx.x * 4 + wave;
    float tw[6]; int id[6];
    #pragma unroll
    for (int j = 0; j < 6; j++) {
        tw[j] = tv[n * 6 + j];
        int t = ti[n * 6 + j];
        id[j] = ((unsigned)t < 8192u) ? t : 0;
    }
    float mx = tw[0];
    #pragma unroll
    for (int j = 1; j < 6; j++) mx = fmaxf(mx, tw[j]);
    float p[6]; float ps = 0.f;
    #pragma unroll
    for (int j = 0; j < 6; j++) { p[j] = __expf(tw[j] - mx); ps += p[j]; }
    float inv = 1.0f / ps;
    #pragma unroll
    for (int j = 0; j < 6; j++) p[j] *= inv;

    const size_t base = (size_t)n * 512 + lane * 8;
    float eh[8];
    { bh8 v = *(const bh8*)(eH + base);
      #pragma unroll
      for (int c = 0; c < 8; c++) eh[c] = (float)v[c]; }
    float nb[6][8];
    #pragma unroll
    for (int j = 0; j < 6; j++) {
        bh8 v = *(const bh8*)(eT + (size_t)id[j] * 512 + lane * 8);
        #pragma unroll
        for (int c = 0; c < 8; c++) nb[j][c] = (float)v[c];
    }
    float ka[6];
    #pragma unroll
    for (int j = 0; j < 6; j++) {
        float s = 0.f;
        #pragma unroll
        for (int c = 0; c < 8; c++) {
            float e = p[j] * nb[j][c] + (1.f - p[j]) * eh[c];
            float x = eh[c] + e;
            x = fminf(fmaxf(x, -15.f), 15.f);
            float ex = __expf(2.f * x);
            float g = 1.f - 2.f / (ex + 1.f);   // tanh
            s += nb[j][c] * g;
        }
        #pragma unroll
        for (int off = 32; off > 0; off >>= 1) s += __shfl_down(s, off);
        ka[j] = __shfl(s, 0);
    }
    float m2 = ka[0];
    #pragma unroll
    for (int j = 1; j < 6; j++) m2 = fmaxf(m2, ka[j]);
    float kp[6]; float ks = 0.f;
    #pragma unroll
    for (int j = 0; j < 6; j++) { kp[j] = __expf(ka[j] - m2); ks += kp[j]; }
    float inv2 = 1.0f / ks;
    #pragma unroll
    for (int j = 0; j < 6; j++) kp[j] *= inv2;
    bh8 o1, o2;
    #pragma unroll
    for (int c = 0; c < 8; c++) {
        float eN = 0.f;
        #pragma unroll
        for (int j = 0; j < 6; j++) eN += kp[j] * nb[j][c];
        o1[c] = (bh)(eh[c] + eN);
        o2[c] = (bh)(eh[c] * eN);
    }
    *(bh8*)(s1 + base) = o1;
    *(bh8*)(s2 + base) = o2;
}

// ---------------------------------------------------------------------------
__global__ void colsum_kernel(const u16* __restrict__ h, float* __restrict__ colsum) {
    int tid = threadIdx.x;
    int n0 = blockIdx.x * 32;
    float a0 = 0.f, a1 = 0.f;
    for (int k = 0; k < 32; k++) {
        size_t b = (size_t)(n0 + k) * 512;
        a0 += bf2f(h[b + tid]); a1 += bf2f(h[b + tid + 256]);
    }
    atomicAdd(&colsum[tid], a0);
    atomicAdd(&colsum[tid + 256], a1);
}

__global__ void meanmix_kernel(u16* __restrict__ h, const float* __restrict__ colsum) {
    size_t i = ((size_t)blockIdx.x * 256 + threadIdx.x) * 8;
    int col = (int)(i & 511);
    union { int4 v; u16 s[8]; } u;
    u.v = *(const int4*)&h[i];
    #pragma unroll
    for (int j = 0; j < 8; j++)
        u.s[j] = f2bf((bf2f(u.s[j]) + colsum[col + j] * (1.0f / 8192.0f)) * 0.5f);
    *(int4*)&h[i] = u.v;
}

__global__ __launch_bounds__(256) void att2_kernel(
    const float* __restrict__ a1, const float* __restrict__ w,
    const float* __restrict__ b, float* __restrict__ att)
{
    int row = blockIdx.x * 4 + (threadIdx.x >> 6);
    int lane = threadIdx.x & 63;
    const float* pr = a1 + (size_t)row * 256;
    float s = 0.f;
    #pragma unroll
    for (int k = 0; k < 4; k++) { int c = lane + k * 64; s += pr[c] * w[c]; }
    #pragma unroll
    for (int off = 32; off > 0; off >>= 1) s += __shfl_down(s, off);
    if (lane == 0) att[row] = s + b[0];
}

// parallel softmax stats: ordered-u32 atomicMax, then atomicAdd of exp sums
__global__ void att_max(const float* __restrict__ att, u32* __restrict__ scal_u) {
    int i = blockIdx.x * 256 + threadIdx.x;
    int lane = threadIdx.x & 63;
    u32 o = ordf(att[i]);
    #pragma unroll
    for (int off = 32; off > 0; off >>= 1) o = max(o, (u32)__shfl_down((int)o, off));
    if (lane == 0) atomicMax(&scal_u[0], o);
}
__global__ void att_sum(const float* __restrict__ att, float* __restrict__ scal) {
    int i = blockIdx.x * 256 + threadIdx.x;
    int lane = threadIdx.x & 63;
    float mx = unordf(((const u32*)scal)[0]);
    float e = __expf(att[i] - mx);
    #pragma unroll
    for (int off = 32; off > 0; off >>= 1) e += __shfl_down(e, off);
    if (lane == 0) atomicAdd(&scal[1], e);
}

__global__ void pooled_kernel(const u16* __restrict__ emb, const float* __restrict__ att,
                              const float* __restrict__ scal, float* __restrict__ pooled) {
    int tid = threadIdx.x;
    int n0 = blockIdx.x * 32;
    float mx = unordf(((const u32*)scal)[0]);
    float inv = 1.0f / scal[1];
    float a0 = 0.f, a1 = 0.f;
    for (int k = 0; k < 32; k++) {
        int n = n0 + k;
        float w = __expf(att[n] - mx) * inv;
        size_t b = (size_t)n * 512;
        a0 += w * bf2f(emb[b + tid]);
        a1 += w * bf2f(emb[b + tid + 256]);
    }
    atomicAdd(&pooled[tid], a0);
    atomicAdd(&pooled[tid + 256], a1);
}

__global__ void final_kernel(const float* __restrict__ pooled,
                             const float* __restrict__ g, const float* __restrict__ bln,
                             const float* __restrict__ fcw, const float* __restrict__ fcb,
                             float* __restrict__ out) {
    __shared__ float red[256];
    int tid = threadIdx.x;
    float x0 = pooled[tid], x1 = pooled[tid + 256];
    red[tid] = x0 + x1; __syncthreads();
    for (int s = 128; s > 0; s >>= 1) { if (tid < s) red[tid] += red[tid + s]; __syncthreads(); }
    float mu = red[0] * (1.0f / 512.0f); __syncthreads();
    float d0 = x0 - mu, d1 = x1 - mu;
    red[tid] = d0 * d0 + d1 * d1; __syncthreads();
    for (int s = 128; s > 0; s >>= 1) { if (tid < s) red[tid] += red[tid + s]; __syncthreads(); }
    float var = red[0] * (1.0f / 512.0f); __syncthreads();
    float rstd = rsqrtf(var + 1e-5f);
    float l0 = d0 * rstd * g[tid]       + bln[tid];
    float l1 = d1 * rstd * g[tid + 256] + bln[tid + 256];
    red[tid] = l0 * fcw[tid * 2] + l1 * fcw[(tid + 256) * 2]; __syncthreads();
    for (int s = 128; s > 0; s >>= 1) { if (tid < s) red[tid] += red[tid + s]; __syncthreads(); }
    float o0 = red[0] + fcb[0]; __syncthreads();
    red[tid] = l0 * fcw[tid * 2 + 1] + l1 * fcw[(tid + 256) * 2 + 1]; __syncthreads();
    for (int s = 128; s > 0; s >>= 1) { if (tid < s) red[tid] += red[tid + s]; __syncthreads(); }
    float o1 = red[0] + fcb[1];
    if (tid == 0) {
        float m = fmaxf(o0, o1);
        float e0 = expf(o0 - m), e1 = expf(o1 - m);
        float se = e0 + e1;
        out[0] = o0;
        out[1] = o1;
        out[2] = e0 / se;
        out[3] = e1 / se;
        out[4] = (o0 >= o1) ? 0.0f : 1.0f;
    }
}

// ---------------------------------------------------------------------------
extern "C" void kernel_launch(void* const* d_in, const int* in_sizes, int n_in,
                              void* d_out, int out_size, void* d_ws, size_t ws_size,
                              hipStream_t stream)
{
    const float* x      = (const float*)d_in[0];
    const float* fc1_w  = (const float*)d_in[1];
    const float* fc1_b  = (const float*)d_in[2];
    const float* wh_w   = (const float*)d_in[3];
    const float* wh_b   = (const float*)d_in[4];
    const float* wt_w   = (const float*)d_in[5];
    const float* wt_b   = (const float*)d_in[6];
    const float* lin1_w = (const float*)d_in[7];
    const float* lin1_b = (const float*)d_in[8];
    const float* lin2_w = (const float*)d_in[9];
    const float* lin2_b = (const float*)d_in[10];
    const float* att1_w = (const float*)d_in[11];
    const float* att1_b = (const float*)d_in[12];
    const float* att2_w = (const float*)d_in[13];
    const float* att2_b = (const float*)d_in[14];
    const float* ln_g   = (const float*)d_in[15];
    const float* ln_b   = (const float*)d_in[16];
    const float* fc_w   = (const float*)d_in[17];
    const float* fc_b   = (const float*)d_in[18];
    float* out = (float*)d_out;
    char* ws = (char*)d_ws;

    u16*   fc1T   = (u16*)(ws + 0);
    u16*   whT    = (u16*)(ws + 1048576);
    u16*   wtT    = (u16*)(ws + 1572864);
    u16*   l1T    = (u16*)(ws + 2097152);
    u16*   l2T    = (u16*)(ws + 2621440);
    u16*   a1T    = (u16*)(ws + 3145728);
    float* tv     = (float*)(ws + 3407872);
    int*   ti     = (int*)(ws + 3604480);
    float* att    = (float*)(ws + 3801088);
    float* colsum = (float*)(ws + 3833856);
    float* pooled = (float*)(ws + 3835904);
    float* scal   = (float*)(ws + 3837952);
    u32*   tvp    = (u32*)(ws + 4194304);
    u16*   hbf    = (u16*)(ws + 14680064);   // 8 MB  [h; later s1]
    u16*   ehbf   = (u16*)(ws + 23068672);   // 8 MB  [e_h; later a1 fp32]
    u16*   etbf   = (u16*)(ws + 31457280);   // 8 MB  [e_t; later emb]
    u16*   s2bf   = (u16*)(ws + 39845888);   // 8 MB  [s2]
    u16*   xbf    = (u16*)(ws + 23068672);   // 16 MB (x bf16; dead after fc1)
    float* a1f    = (float*)(ws + 23068672); // 8 MB fp32 (after e_h dead)

    transpose_cvt<<<5760, dim3(32, 8), 0, stream>>>(
        fc1_w, fc1T, wh_w, whT, wt_w, wtT, lin1_w, l1T, lin2_w, l2T, att1_w, a1T, x, xbf);
    hipMemsetAsync(colsum, 0, 4160, stream);   // colsum + pooled + scal

    gemm_gl<1, 0, 1024><<<dim3(4, 64), 256, 0, stream>>>(xbf, fc1T, fc1_b, nullptr, hbf, 512);
    colsum_kernel<<<256, 256, 0, stream>>>(hbf, colsum);
    meanmix_kernel<<<2048, 256, 0, stream>>>(hbf, colsum);

    ehet_gl<<<dim3(8, 64), 256, 0, stream>>>(hbf, whT, wtT, wh_b, wt_b, ehbf, etbf);

    logits_topk<<<dim3(32, 64), 256, 0, stream>>>(ehbf, etbf, tvp);
    topk_merge<<<128, 64, 0, stream>>>(tvp, tv, ti);

    neighbor_kernel<<<2048, 256, 0, stream>>>(ehbf, etbf, tv, ti, hbf, s2bf);

    lin12_gl<<<dim3(4, 64), 256, 0, stream>>>(hbf, l1T, lin1_b, s2bf, l2T, lin2_b, etbf);

    gemm_gl<2, 1, 512><<<dim3(2, 64), 256, 0, stream>>>(etbf, a1T, att1_b, a1f, nullptr, 256);
    att2_kernel<<<2048, 256, 0, stream>>>(a1f, att2_w, att2_b, att);
    att_max<<<32, 256, 0, stream>>>(att, (u32*)scal);
    att_sum<<<32, 256, 0, stream>>>(att, scal);
    pooled_kernel<<<256, 256, 0, stream>>>(etbf, att, scal, pooled);

    final_kernel<<<1, 256, 0, stream>>>(pooled, ln_g, ln_b, fc_w, fc_b, out);
}